// Round 7
// baseline (342.136 us; speedup 1.0000x reference)
//
#include <hip/hip_runtime.h>

// TinyMambaMulti: B=4, L=4096, D_MODEL=64, D_INNER=128, D_STATE=16, DT_RANK=4,
// D_CONV=4, N_LAYERS=2, OUT=6. All fp32.
// Latency-bound: split kernels, max occupancy, min dispatch count (10 launches).

#define NB 4
#define SL 4096
#define NC 256           // scan chunks per sequence
#define CT 16            // steps per chunk (NC*CT == SL)

__device__ __forceinline__ float siluf(float x) { return x / (1.f + __expf(-x)); }
__device__ __forceinline__ float softplusf(float x) { return x > 20.f ? x : log1pf(__expf(x)); }

// ---------------- linear_in: h[r][64] = x[r][57] @ w[64][57]^T + b; also zeroes pool ---------
__global__ __launch_bounds__(256) void k_linin(const float* __restrict__ x, const float* __restrict__ w,
                                               const float* __restrict__ bias, float* __restrict__ h,
                                               float* __restrict__ pool) {
  __shared__ __align__(16) float xs[64][60];
  __shared__ __align__(16) float ws[64][60];
  const int t = threadIdx.x;
  const int r0 = blockIdx.x * 64;
  if (blockIdx.x == 0) pool[t] = 0.f;     // 256 floats: pool[4][64]
  for (int i = t; i < 64 * 57; i += 256) {
    int r = i / 57, k = i - r * 57;
    xs[r][k] = x[(r0 + r) * 57 + k];
    ws[r][k] = w[i];
  }
  for (int i = t; i < 64 * 3; i += 256) {
    int r = i / 3, j = i - r * 3;
    xs[r][57 + j] = 0.f;
    ws[r][57 + j] = 0.f;
  }
  __syncthreads();
  const int col = t & 63;
  const int rg = t >> 6;
  float wreg[15][4];
#pragma unroll
  for (int k4 = 0; k4 < 15; ++k4) {
    float4 v = *(const float4*)&ws[col][k4 * 4];
    wreg[k4][0] = v.x; wreg[k4][1] = v.y; wreg[k4][2] = v.z; wreg[k4][3] = v.w;
  }
  const float bcol = bias[col];
  for (int g = 0; g < 4; ++g) {
    const int rb = rg * 16 + g * 4;
    float acc[4] = {bcol, bcol, bcol, bcol};
#pragma unroll
    for (int k4 = 0; k4 < 15; ++k4) {
#pragma unroll
      for (int i = 0; i < 4; ++i) {
        float4 xv = *(const float4*)&xs[rb + i][k4 * 4];
        acc[i] = fmaf(xv.x, wreg[k4][0], acc[i]);
        acc[i] = fmaf(xv.y, wreg[k4][1], acc[i]);
        acc[i] = fmaf(xv.z, wreg[k4][2], acc[i]);
        acc[i] = fmaf(xv.w, wreg[k4][3], acc[i]);
      }
    }
#pragma unroll
    for (int i = 0; i < 4; ++i) h[(r0 + rb + i) * 64 + col] = acc[i];
  }
}

// ---------------- in_proj: [16384x256] = h[16384x64] @ W[256x64]^T, split xp/z ----------------
__global__ __launch_bounds__(256) void k_inproj(const float* __restrict__ hin, const float* __restrict__ W,
                                                float* __restrict__ xp, float* __restrict__ z) {
  __shared__ __align__(16) float ht[64][68];
  __shared__ __align__(16) float wt[64][68];
  const int t = threadIdx.x;
  const int r0 = blockIdx.x * 64;
  const int c0 = blockIdx.y * 64;
  for (int idx = t; idx < 64 * 16; idx += 256) {
    int r = idx >> 4, k4 = idx & 15;
    float4 v = *(const float4*)(hin + (r0 + r) * 64 + 4 * k4);
    ht[4 * k4 + 0][r] = v.x; ht[4 * k4 + 1][r] = v.y; ht[4 * k4 + 2][r] = v.z; ht[4 * k4 + 3][r] = v.w;
  }
  for (int idx = t; idx < 64 * 16; idx += 256) {
    int c = idx >> 4, k4 = idx & 15;
    float4 v = *(const float4*)(W + (c0 + c) * 64 + 4 * k4);
    wt[4 * k4 + 0][c] = v.x; wt[4 * k4 + 1][c] = v.y; wt[4 * k4 + 2][c] = v.z; wt[4 * k4 + 3][c] = v.w;
  }
  __syncthreads();
  const int tc = t & 15, tr = t >> 4;
  float acc[4][4] = {};
  for (int k = 0; k < 64; ++k) {
    float4 a = *(const float4*)&ht[k][4 * tr];
    float4 b = *(const float4*)&wt[k][4 * tc];
    float av[4] = {a.x, a.y, a.z, a.w};
    float bv[4] = {b.x, b.y, b.z, b.w};
#pragma unroll
    for (int i = 0; i < 4; ++i)
#pragma unroll
      for (int j = 0; j < 4; ++j) acc[i][j] = fmaf(av[i], bv[j], acc[i][j]);
  }
#pragma unroll
  for (int i = 0; i < 4; ++i) {
    int row = r0 + 4 * tr + i;
    int c = c0 + 4 * tc;
    float4 v = make_float4(acc[i][0], acc[i][1], acc[i][2], acc[i][3]);
    if (c0 < 128) *(float4*)(xp + row * 128 + c) = v;
    else          *(float4*)(z + row * 128 + (c - 128)) = v;
  }
}

// ---------------- K_mid: conv+silu + x_proj + dt_proj + chunk-local scan ----------------
// LDS 19.4 KB; xpw read from global (L2-hot, 18KB). Publishes Hl + dtsum (no chP).
__global__ __launch_bounds__(256, 6) void k_mid(const float* __restrict__ xp, const float* __restrict__ cw,
                                                const float* __restrict__ cb, const float* __restrict__ xpw,
                                                const float* __restrict__ dpw, const float* __restrict__ dpb,
                                                const float* __restrict__ Alog,
                                                float* __restrict__ u_g, float* __restrict__ dl_g,
                                                float* __restrict__ B_g, float* __restrict__ C_g,
                                                float* __restrict__ chH, float* __restrict__ dtsumG) {
  __shared__ __align__(16) float ush[16][132];
  __shared__ __align__(16) float dsh[16][132];
  __shared__ __align__(16) float dbl[16][40];

  const int t = threadIdx.x;
  const int c = blockIdx.x;          // chunk 0..255
  const int b = blockIdx.y;          // batch 0..3
  const int grow0 = b * SL + c * CT;

  // conv + silu -> u (direct global reads; halo rows from prev chunk via pointer math)
  for (int i = t; i < 16 * 128; i += 256) {
    int r = i >> 7, dd = i & 127;
    float4 cwv = *(const float4*)(cw + dd * 4);
    const float* base = xp + (size_t)(grow0 + r) * 128 + dd;
    int l = c * CT + r;
    float acc = cb[dd] + base[0] * cwv.w;
    if (l >= 1) acc += base[-128] * cwv.z;
    if (l >= 2) acc += base[-256] * cwv.y;
    if (l >= 3) acc += base[-384] * cwv.x;
    float uu = siluf(acc);
    ush[r][dd] = uu;
    u_g[(size_t)(grow0 + r) * 128 + dd] = uu;
  }
  __syncthreads();

  // x_proj -> dbl[16][36]; weights straight from global (L2)
  if (t < 144) {
    int r = t / 9, cg = t - (t / 9) * 9;
    int cc = cg * 4;
    const float4* w0 = (const float4*)(xpw + (cc + 0) * 128);
    const float4* w1 = (const float4*)(xpw + (cc + 1) * 128);
    const float4* w2 = (const float4*)(xpw + (cc + 2) * 128);
    const float4* w3 = (const float4*)(xpw + (cc + 3) * 128);
    float a0 = 0, a1 = 0, a2 = 0, a3 = 0;
#pragma unroll 8
    for (int k4 = 0; k4 < 32; ++k4) {
      float4 uu = *(const float4*)&ush[r][4 * k4];
      float4 v0 = w0[k4], v1 = w1[k4], v2 = w2[k4], v3 = w3[k4];
      a0 += uu.x * v0.x + uu.y * v0.y + uu.z * v0.z + uu.w * v0.w;
      a1 += uu.x * v1.x + uu.y * v1.y + uu.z * v1.z + uu.w * v1.w;
      a2 += uu.x * v2.x + uu.y * v2.y + uu.z * v2.z + uu.w * v2.w;
      a3 += uu.x * v3.x + uu.y * v3.y + uu.z * v3.z + uu.w * v3.w;
    }
    dbl[r][cc + 0] = a0; dbl[r][cc + 1] = a1; dbl[r][cc + 2] = a2; dbl[r][cc + 3] = a3;
  }
  __syncthreads();

  // dt_proj + softplus -> delta; export B/C for k_back
  for (int i = t; i < 16 * 128; i += 256) {
    int r = i >> 7, dd = i & 127;
    float4 wv = *(const float4*)(dpw + dd * 4);
    float acc = dpb[dd] + dbl[r][0] * wv.x + dbl[r][1] * wv.y + dbl[r][2] * wv.z + dbl[r][3] * wv.w;
    float dt = softplusf(acc);
    dsh[r][dd] = dt;
    dl_g[(size_t)(grow0 + r) * 128 + dd] = dt;
  }
  for (int i = t; i < 16 * 32; i += 256) {
    int r = i >> 5, j = i & 31;
    float v = dbl[r][4 + j];
    if (j < 16) B_g[(grow0 + r) * 16 + j] = v;
    else        C_g[(grow0 + r) * 16 + (j - 16)] = v;
  }
  __syncthreads();

  // chunk-local scan (thread = (d, half); 8 states each)
  {
    const int d = t & 127, hf = t >> 7, n0 = hf * 8;
    float a[8], hst[8];
#pragma unroll
    for (int j = 0; j < 8; ++j) {
      a[j] = -__expf(Alog[d * 16 + n0 + j]);
      hst[j] = 0.f;
    }
    float dts = 0.f;
#pragma unroll 4
    for (int tt = 0; tt < CT; ++tt) {
      float dt = dsh[tt][d];
      float du = dt * ush[tt][d];
      dts += dt;
#pragma unroll
      for (int j = 0; j < 8; ++j) {
        float e = __expf(dt * a[j]);
        hst[j] = fmaf(e, hst[j], du * dbl[tt][4 + n0 + j]);
      }
    }
    // coalesced layout: chH[((b*NC + c)*128 + d)*16 + n]
    size_t off = ((size_t)(b * NC + c) * 128 + d) * 16 + n0;
    *(float4*)(chH + off + 0) = make_float4(hst[0], hst[1], hst[2], hst[3]);
    *(float4*)(chH + off + 4) = make_float4(hst[4], hst[5], hst[6], hst[7]);
    if (hf == 0) dtsumG[(b * NC + c) * 128 + d] = dts;
  }
}

// ---------------- scan2p: two-level carry propagation, block per (b,d) ----------------
// P recomputed from dtsum: P = exp(dtsum*A) (same formula k_mid used before). In-place carry-in.
__global__ __launch_bounds__(256) void k_scan2p(const float* __restrict__ Alog,
                                                const float* __restrict__ dtsumG, float* chH) {
  __shared__ float sP[16][16];   // [g][n]
  __shared__ float sH[16][16];
  const int t = threadIdx.x;
  const int n = t & 15, g = t >> 4;
  const int d = blockIdx.x, b = blockIdx.y;
  const float A2 = -__expf(Alog[d * 16 + n]);

  float el[16], Hl[16];
  float cp = 1.f, ch = 0.f;
#pragma unroll
  for (int i = 0; i < 16; ++i) {
    int cc = g * 16 + i;
    float ds = dtsumG[(b * NC + cc) * 128 + d];
    float e = __expf(ds * A2);
    float H = chH[((size_t)(b * NC + cc) * 128 + d) * 16 + n];
    el[i] = e; Hl[i] = H;
    ch = fmaf(e, ch, H);
    cp *= e;
  }
  sP[g][n] = cp; sH[g][n] = ch;
  __syncthreads();
#pragma unroll
  for (int s = 1; s < 16; s <<= 1) {
    float pL = 1.f, hL = 0.f;
    if (g >= s) { pL = sP[g - s][n]; hL = sH[g - s][n]; }
    __syncthreads();
    ch = fmaf(cp, hL, ch);
    cp = cp * pL;
    sP[g][n] = cp; sH[g][n] = ch;
    __syncthreads();
  }
  float carry = 0.f;
  if (g > 0) carry = sH[g - 1][n];
#pragma unroll
  for (int i = 0; i < 16; ++i) {
    size_t idx = ((size_t)(b * NC + g * 16 + i) * 128 + d) * 16 + n;
    chH[idx] = carry;                      // becomes carry-in for this chunk
    carry = fmaf(el[i], carry, Hl[i]);
  }
}

// ---------------- K_back: replay + gate + out_proj (opw direct) + residual + fused pool -------
// LDS 28.9 KB -> 5 blocks/CU. Lane-paired state split, shfl_xor combine.
__global__ __launch_bounds__(256, 5) void k_back(const float* __restrict__ u_g, const float* __restrict__ dl_g,
                                                 const float* __restrict__ B_g, const float* __restrict__ C_g,
                                                 const float* __restrict__ z_g, const float* __restrict__ cin,
                                                 const float* __restrict__ Alog, const float* __restrict__ Dsk,
                                                 const float* __restrict__ opw, float* __restrict__ h,
                                                 float* __restrict__ pool, int doPool) {
  __shared__ __align__(16) float ush[16][132];
  __shared__ __align__(16) float dsh[16][132];
  __shared__ float bsh[16][16];
  __shared__ float csh[16][16];
  __shared__ __align__(16) float ygsh[128][20];

  const int t = threadIdx.x;
  const int c = blockIdx.x;
  const int b = blockIdx.y;
  const int grow0 = b * SL + c * CT;

  for (int i = t; i < 16 * 128; i += 256) {
    int r = i >> 7, dd = i & 127;
    ush[r][dd] = u_g[(size_t)(grow0 + r) * 128 + dd];
    dsh[r][dd] = dl_g[(size_t)(grow0 + r) * 128 + dd];
  }
  for (int i = t; i < 16 * 32; i += 256) {
    int r = i >> 5, j = i & 31;
    if (j < 16) bsh[r][j] = B_g[(grow0 + r) * 16 + j];
    else        csh[r][j - 16] = C_g[(grow0 + r) * 16 + (j - 16)];
  }
  __syncthreads();

  // replay scan + D-skip + silu(z) gate; lane pair (d = t>>1, hf = t&1)
  {
    const int d = t >> 1, hf = t & 1, n0 = hf * 8;
    float a[8], hst[8];
    size_t off = ((size_t)(b * NC + c) * 128 + d) * 16 + n0;
    float4 h0 = *(const float4*)(cin + off + 0);
    float4 h1 = *(const float4*)(cin + off + 4);
    hst[0] = h0.x; hst[1] = h0.y; hst[2] = h0.z; hst[3] = h0.w;
    hst[4] = h1.x; hst[5] = h1.y; hst[6] = h1.z; hst[7] = h1.w;
#pragma unroll
    for (int j = 0; j < 8; ++j) a[j] = -__expf(Alog[d * 16 + n0 + j]);
    const float Dd = Dsk[d];
#pragma unroll 4
    for (int tt = 0; tt < CT; ++tt) {
      float dt = dsh[tt][d];
      float ut = ush[tt][d];
      float du = dt * ut;
      float yv = 0.f;
#pragma unroll
      for (int j = 0; j < 8; ++j) {
        float e = __expf(dt * a[j]);
        hst[j] = fmaf(e, hst[j], du * bsh[tt][n0 + j]);
        yv = fmaf(hst[j], csh[tt][n0 + j], yv);
      }
      float tot = yv + __shfl_xor(yv, 1);
      if (hf == 0) {
        float y = tot + ut * Dd;
        float zv = z_g[(size_t)(grow0 + tt) * 128 + d];
        ygsh[d][tt] = y * siluf(zv);
      }
    }
  }
  __syncthreads();

  // out_proj full-K per thread (opw [64][128] direct, float4 over k) + residual + pool
  {
    const int o = t & 63, q = t >> 6;     // rows q*4 .. q*4+3
    float acc0 = 0.f, acc1 = 0.f, acc2 = 0.f, acc3 = 0.f;
#pragma unroll 8
    for (int k4 = 0; k4 < 32; ++k4) {
      float4 w4 = *(const float4*)(opw + o * 128 + 4 * k4);
      float4 y0 = *(const float4*)&ygsh[4 * k4 + 0][q * 4];
      float4 y1 = *(const float4*)&ygsh[4 * k4 + 1][q * 4];
      float4 y2 = *(const float4*)&ygsh[4 * k4 + 2][q * 4];
      float4 y3 = *(const float4*)&ygsh[4 * k4 + 3][q * 4];
      acc0 = fmaf(y0.x, w4.x, acc0); acc0 = fmaf(y1.x, w4.y, acc0);
      acc0 = fmaf(y2.x, w4.z, acc0); acc0 = fmaf(y3.x, w4.w, acc0);
      acc1 = fmaf(y0.y, w4.x, acc1); acc1 = fmaf(y1.y, w4.y, acc1);
      acc1 = fmaf(y2.y, w4.z, acc1); acc1 = fmaf(y3.y, w4.w, acc1);
      acc2 = fmaf(y0.z, w4.x, acc2); acc2 = fmaf(y1.z, w4.y, acc2);
      acc2 = fmaf(y2.z, w4.z, acc2); acc2 = fmaf(y3.z, w4.w, acc2);
      acc3 = fmaf(y0.w, w4.x, acc3); acc3 = fmaf(y1.w, w4.y, acc3);
      acc3 = fmaf(y2.w, w4.z, acc3); acc3 = fmaf(y3.w, w4.w, acc3);
    }
    size_t row = (size_t)(grow0 + q * 4) * 64 + o;
    float h0 = h[row + 0 * 64] + acc0;
    float h1 = h[row + 1 * 64] + acc1;
    float h2 = h[row + 2 * 64] + acc2;
    float h3 = h[row + 3 * 64] + acc3;
    h[row + 0 * 64] = h0; h[row + 1 * 64] = h1;
    h[row + 2 * 64] = h2; h[row + 3 * 64] = h3;
    if (doPool) atomicAdd(pool + b * 64 + o, h0 + h1 + h2 + h3);
  }
}

// ---------------- classifier from pooled sums ----------------
__global__ __launch_bounds__(64) void k_cls(const float* __restrict__ pool, const float* __restrict__ wc,
                                            const float* __restrict__ bc, float* __restrict__ out) {
  const int t = threadIdx.x;
  if (t < 24) {
    int bb = t / 6, o = t - bb * 6;
    float acc = 0.f;
    for (int d2 = 0; d2 < 64; ++d2) acc += pool[bb * 64 + d2] * wc[o * 64 + d2];
    out[bb * 6 + o] = bc[o] + acc * (1.f / 4096.f);
  }
}

extern "C" void kernel_launch(void* const* d_in, const int* in_sizes, int n_in,
                              void* d_out, int out_size, void* d_ws, size_t ws_size,
                              hipStream_t stream) {
  const float* x    = (const float*)d_in[0];
  const float* w_in = (const float*)d_in[1];
  const float* b_in = (const float*)d_in[2];
  const float* ipw  = (const float*)d_in[3];
  const float* cw   = (const float*)d_in[4];
  const float* cb   = (const float*)d_in[5];
  const float* xpw  = (const float*)d_in[6];
  const float* dpw  = (const float*)d_in[7];
  const float* dpb  = (const float*)d_in[8];
  const float* Alog = (const float*)d_in[9];
  const float* Dsk  = (const float*)d_in[10];
  const float* opw  = (const float*)d_in[11];
  const float* wc   = (const float*)d_in[12];
  const float* bc   = (const float*)d_in[13];
  float* out = (float*)d_out;

  float* ws    = (float*)d_ws;
  float* h     = ws;                    // 1048576
  float* xp    = h + 1048576;           // 2097152
  float* zb    = xp + 2097152;          // 2097152
  float* ub    = zb + 2097152;          // 2097152
  float* dl    = ub + 2097152;          // 2097152
  float* Bb    = dl + 2097152;          // 262144
  float* Cb    = Bb + 262144;           // 262144
  float* chH   = Cb + 262144;           // 2097152 (Hl -> carry-in in place)
  float* dtsum = chH + 2097152;         // 131072
  float* pool  = dtsum + 131072;        // 256 (zeroed by k_linin)

  k_linin<<<256, 256, 0, stream>>>(x, w_in, b_in, h, pool);
  for (int i = 0; i < 2; ++i) {
    k_inproj<<<dim3(256, 4), 256, 0, stream>>>(h, ipw + i * 16384, xp, zb);
    k_mid<<<dim3(NC, 4), 256, 0, stream>>>(xp, cw + i * 512, cb + i * 128,
                                           xpw + i * 4608, dpw + i * 512, dpb + i * 128,
                                           Alog + i * 2048, ub, dl, Bb, Cb, chH, dtsum);
    k_scan2p<<<dim3(128, 4), 256, 0, stream>>>(Alog + i * 2048, dtsum, chH);
    k_back<<<dim3(NC, 4), 256, 0, stream>>>(ub, dl, Bb, Cb, zb, chH,
                                            Alog + i * 2048, Dsk + i * 128,
                                            opw + i * 8192, h, pool, i == 1 ? 1 : 0);
  }
  k_cls<<<1, 64, 0, stream>>>(pool, wc, bc, out);
}

// Round 8
// 302.791 us; speedup vs baseline: 1.1299x; 1.1299x over previous
//
#include <hip/hip_runtime.h>

// TinyMambaMulti: B=4, L=4096, D_MODEL=64, D_INNER=128, D_STATE=16, DT_RANK=4,
// D_CONV=4, N_LAYERS=2, OUT=6. All fp32.
// Structure: 8 dispatches. linin(+inproj0+opwT+poolzero) -> [mid, scan2p, back(+inproj_next|pool)]x2 -> cls.
// Lessons: stage inner-loop operands in LDS; don't squeeze VGPR below ~64 (r7);
// no cooperative mega-fusion (r5); scan is latency-bound -> occupancy + fewer dispatches.

#define NB 4
#define SL 4096
#define NC 256           // scan chunks per sequence
#define CT 16            // steps per chunk (NC*CT == SL)

__device__ __forceinline__ float siluf(float x) { return x / (1.f + __expf(-x)); }
__device__ __forceinline__ float softplusf(float x) { return x > 20.f ? x : log1pf(__expf(x)); }

// ---------------- k_linin_ip: linear_in + in_proj(layer0) + opwT transpose + pool zero --------
__global__ __launch_bounds__(256) void k_linin_ip(const float* __restrict__ x, const float* __restrict__ w,
                                                  const float* __restrict__ bias, const float* __restrict__ ipw0,
                                                  const float* __restrict__ opw, float* __restrict__ h,
                                                  float* __restrict__ xp, float* __restrict__ z,
                                                  float* __restrict__ opwT, float* __restrict__ pool) {
  __shared__ __align__(16) float ht[64][68];          // h k-major [dmodel k][row]
  __shared__ __align__(16) char pool0[30720];         // xs[64][60]+ws[64][60] | wt[64][68]
  float* xs  = (float*)pool0;          // [64][60]
  float* wsl = xs + 64 * 60;           // [64][60]
  float* wt  = (float*)pool0;          // [64][68] k-major (after linin)

  const int t = threadIdx.x;
  const int r0 = blockIdx.x * 64;

  // opwT transpose: [2][64][128] -> [2][128][64]
  if (t < 64) {
    int i = blockIdx.x * 64 + t;       // 0..16383
    int l = i >> 13, rem = i & 8191;
    int d = rem >> 6, m = rem & 63;
    opwT[i] = opw[l * 8192 + m * 128 + d];
  }
  if (blockIdx.x == 0) pool[t] = 0.f;  // pool[4][64]

  for (int i = t; i < 64 * 57; i += 256) {
    int r = i / 57, k = i - r * 57;
    xs[r * 60 + k] = x[(r0 + r) * 57 + k];
    wsl[r * 60 + k] = w[i];
  }
  for (int i = t; i < 64 * 3; i += 256) {
    int r = i / 3, j = i - r * 3;
    xs[r * 60 + 57 + j] = 0.f;
    wsl[r * 60 + 57 + j] = 0.f;
  }
  __syncthreads();

  // linear_in: thread (col, rg) computes rows rb..rb+3 at column col
  {
    const int col = t & 63;
    const int rg = t >> 6;
    float wreg[15][4];
#pragma unroll
    for (int k4 = 0; k4 < 15; ++k4) {
      float4 v = *(const float4*)&wsl[col * 60 + k4 * 4];
      wreg[k4][0] = v.x; wreg[k4][1] = v.y; wreg[k4][2] = v.z; wreg[k4][3] = v.w;
    }
    const float bcol = bias[col];
    for (int g = 0; g < 4; ++g) {
      const int rb = rg * 16 + g * 4;
      float acc[4] = {bcol, bcol, bcol, bcol};
#pragma unroll
      for (int k4 = 0; k4 < 15; ++k4) {
#pragma unroll
        for (int i = 0; i < 4; ++i) {
          float4 xv = *(const float4*)&xs[(rb + i) * 60 + 4 * k4];
          acc[i] = fmaf(xv.x, wreg[k4][0], acc[i]);
          acc[i] = fmaf(xv.y, wreg[k4][1], acc[i]);
          acc[i] = fmaf(xv.z, wreg[k4][2], acc[i]);
          acc[i] = fmaf(xv.w, wreg[k4][3], acc[i]);
        }
      }
#pragma unroll
      for (int i = 0; i < 4; ++i) {
        h[(r0 + rb + i) * 64 + col] = acc[i];
        ht[col][rb + i] = acc[i];
      }
    }
  }
  __syncthreads();   // ht ready; xs/wsl dead

  // in_proj layer0: 4 col-tiles of 64
  const int tc = t & 15, tr = t >> 4;
  for (int ct4 = 0; ct4 < 4; ++ct4) {
    for (int idx = t; idx < 64 * 16; idx += 256) {
      int c = idx >> 4, k4 = idx & 15;
      float4 v = *(const float4*)(ipw0 + (ct4 * 64 + c) * 64 + 4 * k4);
      wt[(4 * k4 + 0) * 68 + c] = v.x; wt[(4 * k4 + 1) * 68 + c] = v.y;
      wt[(4 * k4 + 2) * 68 + c] = v.z; wt[(4 * k4 + 3) * 68 + c] = v.w;
    }
    __syncthreads();
    float acc[4][4] = {};
    for (int k = 0; k < 64; ++k) {
      float4 a = *(const float4*)&ht[k][4 * tr];
      float4 b = *(const float4*)&wt[k * 68 + 4 * tc];
      float av[4] = {a.x, a.y, a.z, a.w};
      float bv[4] = {b.x, b.y, b.z, b.w};
#pragma unroll
      for (int i = 0; i < 4; ++i)
#pragma unroll
        for (int j = 0; j < 4; ++j) acc[i][j] = fmaf(av[i], bv[j], acc[i][j]);
    }
#pragma unroll
    for (int i = 0; i < 4; ++i) {
      int row = r0 + 4 * tr + i;
      int c = ct4 * 64 + 4 * tc;
      float4 v = make_float4(acc[i][0], acc[i][1], acc[i][2], acc[i][3]);
      if (ct4 < 2) *(float4*)(xp + row * 128 + c) = v;
      else         *(float4*)(z + row * 128 + (c - 128)) = v;
    }
    __syncthreads();
  }
}

// ---------------- K_mid: conv+silu + x_proj + dt_proj + chunk-local scan ----------------
// r6-proven: wsh staged, (256,4), LDS 38.5KB. Exports u, dbl (raw x_proj), Hl, dtsum.
__global__ __launch_bounds__(256, 4) void k_mid(const float* __restrict__ xp, const float* __restrict__ cw,
                                                const float* __restrict__ cb, const float* __restrict__ xpw,
                                                const float* __restrict__ dpw, const float* __restrict__ dpb,
                                                const float* __restrict__ Alog,
                                                float* __restrict__ u_g, float* __restrict__ dbl_g,
                                                float* __restrict__ chH, float* __restrict__ dtsumG) {
  __shared__ __align__(16) float ush[16][132];
  __shared__ __align__(16) float dsh[16][132];
  __shared__ __align__(16) float wsh[36][132];
  __shared__ __align__(16) float dbl[16][40];

  const int t = threadIdx.x;
  const int c = blockIdx.x;
  const int b = blockIdx.y;
  const int grow0 = b * SL + c * CT;

  for (int i = t; i < 36 * 128; i += 256) {
    int cc = i >> 7, dd = i & 127;
    wsh[cc][dd] = xpw[cc * 128 + dd];
  }
  // conv + silu -> u (direct global reads; halo via pointer math)
  for (int i = t; i < 16 * 128; i += 256) {
    int r = i >> 7, dd = i & 127;
    float4 cwv = *(const float4*)(cw + dd * 4);
    const float* base = xp + (size_t)(grow0 + r) * 128 + dd;
    int l = c * CT + r;
    float acc = cb[dd] + base[0] * cwv.w;
    if (l >= 1) acc += base[-128] * cwv.z;
    if (l >= 2) acc += base[-256] * cwv.y;
    if (l >= 3) acc += base[-384] * cwv.x;
    float uu = siluf(acc);
    ush[r][dd] = uu;
    u_g[(size_t)(grow0 + r) * 128 + dd] = uu;
  }
  __syncthreads();

  // x_proj -> dbl[16][36]
  if (t < 144) {
    int r = t / 9, cg = t - (t / 9) * 9;
    int cc = cg * 4;
    float a0 = 0, a1 = 0, a2 = 0, a3 = 0;
#pragma unroll 8
    for (int k4 = 0; k4 < 32; ++k4) {
      float4 uu = *(const float4*)&ush[r][4 * k4];
      float4 w0 = *(const float4*)&wsh[cc + 0][4 * k4];
      float4 w1 = *(const float4*)&wsh[cc + 1][4 * k4];
      float4 w2 = *(const float4*)&wsh[cc + 2][4 * k4];
      float4 w3 = *(const float4*)&wsh[cc + 3][4 * k4];
      a0 += uu.x * w0.x + uu.y * w0.y + uu.z * w0.z + uu.w * w0.w;
      a1 += uu.x * w1.x + uu.y * w1.y + uu.z * w1.z + uu.w * w1.w;
      a2 += uu.x * w2.x + uu.y * w2.y + uu.z * w2.z + uu.w * w2.w;
      a3 += uu.x * w3.x + uu.y * w3.y + uu.z * w3.z + uu.w * w3.w;
    }
    dbl[r][cc + 0] = a0; dbl[r][cc + 1] = a1; dbl[r][cc + 2] = a2; dbl[r][cc + 3] = a3;
  }
  __syncthreads();

  // dt_proj + softplus -> dsh (internal); export dbl
  for (int i = t; i < 16 * 128; i += 256) {
    int r = i >> 7, dd = i & 127;
    float4 wv = *(const float4*)(dpw + dd * 4);
    float acc = dpb[dd] + dbl[r][0] * wv.x + dbl[r][1] * wv.y + dbl[r][2] * wv.z + dbl[r][3] * wv.w;
    dsh[r][dd] = softplusf(acc);
  }
  {
    size_t base = (size_t)(b * NC + c) * 576;
    for (int i = t; i < 576; i += 256) {
      int r = i / 36, cc = i - r * 36;
      dbl_g[base + i] = dbl[r][cc];
    }
  }
  __syncthreads();

  // chunk-local scan (thread = (d, half); 8 states each)
  {
    const int d = t & 127, hf = t >> 7, n0 = hf * 8;
    float a[8], hst[8];
#pragma unroll
    for (int j = 0; j < 8; ++j) {
      a[j] = -__expf(Alog[d * 16 + n0 + j]);
      hst[j] = 0.f;
    }
    float dts = 0.f;
#pragma unroll 4
    for (int tt = 0; tt < CT; ++tt) {
      float dt = dsh[tt][d];
      float du = dt * ush[tt][d];
      dts += dt;
#pragma unroll
      for (int j = 0; j < 8; ++j) {
        float e = __expf(dt * a[j]);
        hst[j] = fmaf(e, hst[j], du * dbl[tt][4 + n0 + j]);
      }
    }
    size_t off = ((size_t)(b * NC + c) * 128 + d) * 16 + n0;
    *(float4*)(chH + off + 0) = make_float4(hst[0], hst[1], hst[2], hst[3]);
    *(float4*)(chH + off + 4) = make_float4(hst[4], hst[5], hst[6], hst[7]);
    if (hf == 0) dtsumG[(b * NC + c) * 128 + d] = dts;
  }
}

// ---------------- scan2p: two-level carry propagation, block per (b,d) ----------------
__global__ __launch_bounds__(256) void k_scan2p(const float* __restrict__ Alog,
                                                const float* __restrict__ dtsumG, float* chH) {
  __shared__ float sP[16][16];
  __shared__ float sH[16][16];
  const int t = threadIdx.x;
  const int n = t & 15, g = t >> 4;
  const int d = blockIdx.x, b = blockIdx.y;
  const float A2 = -__expf(Alog[d * 16 + n]);

  float el[16], Hl[16];
  float cp = 1.f, ch = 0.f;
#pragma unroll
  for (int i = 0; i < 16; ++i) {
    int cc = g * 16 + i;
    float ds = dtsumG[(b * NC + cc) * 128 + d];
    float e = __expf(ds * A2);
    float H = chH[((size_t)(b * NC + cc) * 128 + d) * 16 + n];
    el[i] = e; Hl[i] = H;
    ch = fmaf(e, ch, H);
    cp *= e;
  }
  sP[g][n] = cp; sH[g][n] = ch;
  __syncthreads();
#pragma unroll
  for (int s = 1; s < 16; s <<= 1) {
    float pL = 1.f, hL = 0.f;
    if (g >= s) { pL = sP[g - s][n]; hL = sH[g - s][n]; }
    __syncthreads();
    ch = fmaf(cp, hL, ch);
    cp = cp * pL;
    sP[g][n] = cp; sH[g][n] = ch;
    __syncthreads();
  }
  float carry = 0.f;
  if (g > 0) carry = sH[g - 1][n];
#pragma unroll
  for (int i = 0; i < 16; ++i) {
    size_t idx = ((size_t)(b * NC + g * 16 + i) * 128 + d) * 16 + n;
    chH[idx] = carry;
    carry = fmaf(el[i], carry, Hl[i]);
  }
}

// ---------------- K_back_ip: replay + gate + out_proj + residual + {in_proj(next) | pool} -----
// LDS ~29.3KB -> 5 blocks/CU. mode=0: fuse next layer's in_proj; mode=1: fuse pool atomics.
__global__ __launch_bounds__(256, 5) void k_back_ip(const float* __restrict__ u_g, const float* __restrict__ dbl_g,
                                                    const float* __restrict__ z_g, const float* __restrict__ cin,
                                                    const float* __restrict__ Alog, const float* __restrict__ dpw,
                                                    const float* __restrict__ dpb, const float* __restrict__ Dsk,
                                                    const float* __restrict__ opwT, const float* __restrict__ ipwN,
                                                    float* __restrict__ h, float* __restrict__ xp,
                                                    float* __restrict__ z_out, float* __restrict__ pool, int mode) {
  __shared__ __align__(16) char poolA[8704];    // ush[16][132] 8448 | wt[32][68] 8704
  __shared__ __align__(16) char poolB[21248];   // dsh[16][132]+dblsh[16][40]+ygsh[128][20] | ht2[16][68]
  float* ush   = (float*)poolA;            // [16][132]
  float* wt    = (float*)poolA;            // [32][68]
  float* dsh   = (float*)poolB;            // [16][132]
  float* dblsh = dsh + 16 * 132;           // [16][40]
  float* ygsh  = dblsh + 16 * 40;          // [128][20]
  float* ht2   = (float*)poolB;            // [16][68] (overlaps dead dsh/dblsh, not ygsh)

  const int t = threadIdx.x;
  const int c = blockIdx.x;
  const int b = blockIdx.y;
  const int grow0 = b * SL + c * CT;

  for (int i = t; i < 16 * 128; i += 256) {
    int r = i >> 7, dd = i & 127;
    ush[r * 132 + dd] = u_g[(size_t)(grow0 + r) * 128 + dd];
  }
  {
    size_t base = (size_t)(b * NC + c) * 576;
    for (int i = t; i < 576; i += 256) {
      int r = i / 36, cc = i - r * 36;
      dblsh[r * 40 + cc] = dbl_g[base + i];
    }
  }
  __syncthreads();

  // recompute delta from dbl (bit-identical to k_mid's formula)
  for (int i = t; i < 16 * 128; i += 256) {
    int r = i >> 7, dd = i & 127;
    float4 wv = *(const float4*)(dpw + dd * 4);
    float4 db = *(const float4*)&dblsh[r * 40];
    float acc = dpb[dd] + db.x * wv.x + db.y * wv.y + db.z * wv.z + db.w * wv.w;
    dsh[r * 132 + dd] = softplusf(acc);
  }
  __syncthreads();

  // replay scan + D-skip + silu(z) gate; lane pair (d = t>>1, hf = t&1)
  {
    const int d = t >> 1, hf = t & 1, n0 = hf * 8;
    float a[8], hst[8];
    size_t off = ((size_t)(b * NC + c) * 128 + d) * 16 + n0;
    float4 h0 = *(const float4*)(cin + off + 0);
    float4 h1 = *(const float4*)(cin + off + 4);
    hst[0] = h0.x; hst[1] = h0.y; hst[2] = h0.z; hst[3] = h0.w;
    hst[4] = h1.x; hst[5] = h1.y; hst[6] = h1.z; hst[7] = h1.w;
#pragma unroll
    for (int j = 0; j < 8; ++j) a[j] = -__expf(Alog[d * 16 + n0 + j]);
    const float Dd = Dsk[d];
#pragma unroll 4
    for (int tt = 0; tt < CT; ++tt) {
      float dt = dsh[tt * 132 + d];
      float ut = ush[tt * 132 + d];
      float du = dt * ut;
      float yv = 0.f;
#pragma unroll
      for (int j = 0; j < 8; ++j) {
        float e = __expf(dt * a[j]);
        hst[j] = fmaf(e, hst[j], du * dblsh[tt * 40 + 4 + n0 + j]);
        yv = fmaf(hst[j], dblsh[tt * 40 + 20 + n0 + j], yv);
      }
      float tot = yv + __shfl_xor(yv, 1);
      if (hf == 0) {
        float y = tot + ut * Dd;
        float zv = z_g[(size_t)(grow0 + tt) * 128 + d];
        ygsh[d * 20 + tt] = y * siluf(zv);
      }
    }
  }
  __syncthreads();

  // out_proj (opwT coalesced) + residual; stash new h into ht2 (k-major over dmodel)
  {
    const int o = t & 63, q = t >> 6;
    float acc0 = 0.f, acc1 = 0.f, acc2 = 0.f, acc3 = 0.f;
#pragma unroll 8
    for (int k = 0; k < 128; ++k) {
      float w = opwT[k * 64 + o];
      float4 yv = *(const float4*)&ygsh[k * 20 + q * 4];
      acc0 = fmaf(yv.x, w, acc0);
      acc1 = fmaf(yv.y, w, acc1);
      acc2 = fmaf(yv.z, w, acc2);
      acc3 = fmaf(yv.w, w, acc3);
    }
    size_t row = (size_t)(grow0 + q * 4) * 64 + o;
    float h0 = h[row + 0 * 64] + acc0;
    float h1 = h[row + 1 * 64] + acc1;
    float h2 = h[row + 2 * 64] + acc2;
    float h3 = h[row + 3 * 64] + acc3;
    h[row + 0 * 64] = h0; h[row + 1 * 64] = h1;
    h[row + 2 * 64] = h2; h[row + 3 * 64] = h3;
    if (mode == 1) {
      atomicAdd(pool + b * 64 + o, h0 + h1 + h2 + h3);
    } else {
      ht2[(q * 4 + 0) * 68 + o] = h0;
      ht2[(q * 4 + 1) * 68 + o] = h1;
      ht2[(q * 4 + 2) * 68 + o] = h2;
      ht2[(q * 4 + 3) * 68 + o] = h3;
    }
  }

  // fused in_proj for next layer: 8 col-tiles of 32
  if (mode == 0) {
    __syncthreads();
    for (int ct8 = 0; ct8 < 8; ++ct8) {
      const int c0 = ct8 * 32;
      for (int idx = t; idx < 32 * 16; idx += 256) {
        int cc = idx >> 4, k4 = idx & 15;
        *(float4*)&wt[cc * 68 + 4 * k4] = *(const float4*)(ipwN + (c0 + cc) * 64 + 4 * k4);
      }
      __syncthreads();
      for (int i = t; i < 16 * 32; i += 256) {
        int r = i >> 5, cc = i & 31;
        float acc = 0.f;
#pragma unroll
        for (int k4 = 0; k4 < 16; ++k4) {
          float4 hv = *(const float4*)&ht2[r * 68 + 4 * k4];
          float4 wv = *(const float4*)&wt[cc * 68 + 4 * k4];
          acc += hv.x * wv.x + hv.y * wv.y + hv.z * wv.z + hv.w * wv.w;
        }
        int col = c0 + cc;
        size_t row = (size_t)(grow0 + r);
        if (col < 128) xp[row * 128 + col] = acc;
        else           z_out[row * 128 + (col - 128)] = acc;
      }
      __syncthreads();
    }
  }
}

// ---------------- classifier from pooled sums ----------------
__global__ __launch_bounds__(64) void k_cls(const float* __restrict__ pool, const float* __restrict__ wc,
                                            const float* __restrict__ bc, float* __restrict__ out) {
  const int t = threadIdx.x;
  if (t < 24) {
    int bb = t / 6, o = t - bb * 6;
    float acc = 0.f;
    for (int d2 = 0; d2 < 64; ++d2) acc += pool[bb * 64 + d2] * wc[o * 64 + d2];
    out[bb * 6 + o] = bc[o] + acc * (1.f / 4096.f);
  }
}

extern "C" void kernel_launch(void* const* d_in, const int* in_sizes, int n_in,
                              void* d_out, int out_size, void* d_ws, size_t ws_size,
                              hipStream_t stream) {
  const float* x    = (const float*)d_in[0];
  const float* w_in = (const float*)d_in[1];
  const float* b_in = (const float*)d_in[2];
  const float* ipw  = (const float*)d_in[3];
  const float* cw   = (const float*)d_in[4];
  const float* cb   = (const float*)d_in[5];
  const float* xpw  = (const float*)d_in[6];
  const float* dpw  = (const float*)d_in[7];
  const float* dpb  = (const float*)d_in[8];
  const float* Alog = (const float*)d_in[9];
  const float* Dsk  = (const float*)d_in[10];
  const float* opw  = (const float*)d_in[11];
  const float* wc   = (const float*)d_in[12];
  const float* bc   = (const float*)d_in[13];
  float* out = (float*)d_out;

  float* ws    = (float*)d_ws;
  float* h     = ws;                    // 1048576
  float* xp    = h + 1048576;           // 2097152
  float* zb    = xp + 2097152;          // 2097152 (z in & out, block-disjoint rows)
  float* ub    = zb + 2097152;          // 2097152
  float* dblG  = ub + 2097152;          // 589824 (4*256*576)
  float* chH   = dblG + 589824;         // 2097152 (Hl -> carry-in in place)
  float* dtsum = chH + 2097152;         // 131072
  float* opwT  = dtsum + 131072;        // 16384
  float* pool  = opwT + 16384;          // 256 (zeroed by k_linin_ip)

  k_linin_ip<<<256, 256, 0, stream>>>(x, w_in, b_in, ipw, opw, h, xp, zb, opwT, pool);
  for (int i = 0; i < 2; ++i) {
    k_mid<<<dim3(NC, 4), 256, 0, stream>>>(xp, cw + i * 512, cb + i * 128,
                                           xpw + i * 4608, dpw + i * 512, dpb + i * 128,
                                           Alog + i * 2048, ub, dblG, chH, dtsum);
    k_scan2p<<<dim3(128, 4), 256, 0, stream>>>(Alog + i * 2048, dtsum, chH);
    k_back_ip<<<dim3(NC, 4), 256, 0, stream>>>(ub, dblG, zb, chH,
                                               Alog + i * 2048, dpw + i * 512, dpb + i * 128,
                                               Dsk + i * 128, opwT + i * 8192, ipw + 16384,
                                               h, xp, zb, pool, i == 1 ? 1 : 0);
  }
  k_cls<<<1, 64, 0, stream>>>(pool, wc, bc, out);
}

// Round 9
// 271.278 us; speedup vs baseline: 1.2612x; 1.1162x over previous
//
#include <hip/hip_runtime.h>

// TinyMambaMulti: B=4, L=4096, D_MODEL=64, D_INNER=128, D_STATE=16, DT_RANK=4,
// D_CONV=4, N_LAYERS=2, OUT=6. All fp32.
// 8 dispatches: linin(+ipwT/opwT prep+poolzero) -> [mid_ip, scan2p, back]x2 -> cls.
// Lessons: r5 no coop mega-fusion (spill+2blk/CU); r7 don't squeeze VGPR<64 / don't
// unstage inner-loop operands; r8 don't fuse GEMM into k_back tail (barrier-serial).
// Winning pattern: LDS-resident phase chain at >=4 blocks/CU, coalesced weight layouts.

#define NB 4
#define SL 4096
#define NC 256           // scan chunks per sequence
#define CT 16            // steps per chunk (NC*CT == SL)

__device__ __forceinline__ float siluf(float x) { return x / (1.f + __expf(-x)); }
__device__ __forceinline__ float softplusf(float x) { return x > 20.f ? x : log1pf(__expf(x)); }

// ---------------- k_linin: linear_in -> h; prep ipwT/opwT; zero pool ----------------
__global__ __launch_bounds__(256) void k_linin(const float* __restrict__ x, const float* __restrict__ w,
                                               const float* __restrict__ bias, const float* __restrict__ ipw,
                                               const float* __restrict__ opw, float* __restrict__ h,
                                               float* __restrict__ ipwT, float* __restrict__ opwT,
                                               float* __restrict__ pool) {
  __shared__ __align__(16) float xs[64][60];
  __shared__ __align__(16) float ws[64][60];
  const int t = threadIdx.x;
  const int r0 = blockIdx.x * 64;

  // opwT: [2][64][128] -> [2][128][64] (16384 elems, 64/block)
  if (t < 64) {
    int i = blockIdx.x * 64 + t;
    int l = i >> 13, rem = i & 8191;
    int d = rem >> 6, m = rem & 63;
    opwT[i] = opw[l * 8192 + m * 128 + d];
  }
  // ipwT: [2][256][64] -> [2][64][256] (32768 elems, 128/block)
  if (t < 128) {
    int i = blockIdx.x * 128 + t;
    int l = i >> 14, rem = i & 16383;
    int k = rem >> 8, c = rem & 255;
    ipwT[i] = ipw[l * 16384 + c * 64 + k];
  }
  if (blockIdx.x == 0) pool[t] = 0.f;   // pool[4][64]

  for (int i = t; i < 64 * 57; i += 256) {
    int r = i / 57, k = i - r * 57;
    xs[r][k] = x[(r0 + r) * 57 + k];
    ws[r][k] = w[i];
  }
  for (int i = t; i < 64 * 3; i += 256) {
    int r = i / 3, j = i - r * 3;
    xs[r][57 + j] = 0.f;
    ws[r][57 + j] = 0.f;
  }
  __syncthreads();
  const int col = t & 63;
  const int rg = t >> 6;
  float wreg[15][4];
#pragma unroll
  for (int k4 = 0; k4 < 15; ++k4) {
    float4 v = *(const float4*)&ws[col][k4 * 4];
    wreg[k4][0] = v.x; wreg[k4][1] = v.y; wreg[k4][2] = v.z; wreg[k4][3] = v.w;
  }
  const float bcol = bias[col];
  for (int g = 0; g < 4; ++g) {
    const int rb = rg * 16 + g * 4;
    float acc[4] = {bcol, bcol, bcol, bcol};
#pragma unroll
    for (int k4 = 0; k4 < 15; ++k4) {
#pragma unroll
      for (int i = 0; i < 4; ++i) {
        float4 xv = *(const float4*)&xs[rb + i][k4 * 4];
        acc[i] = fmaf(xv.x, wreg[k4][0], acc[i]);
        acc[i] = fmaf(xv.y, wreg[k4][1], acc[i]);
        acc[i] = fmaf(xv.z, wreg[k4][2], acc[i]);
        acc[i] = fmaf(xv.w, wreg[k4][3], acc[i]);
      }
    }
#pragma unroll
    for (int i = 0; i < 4; ++i) h[(r0 + rb + i) * 64 + col] = acc[i];
  }
}

// ---------------- k_mid_ip: in_proj + conv+silu + x_proj + dt_proj + chunk-local scan --------
// LDS 37.6KB -> 4 blocks/CU. xp lives only in LDS (global xp buffer eliminated).
__global__ __launch_bounds__(256, 4) void k_mid_ip(
    const float* __restrict__ h, const float* __restrict__ ipwT,
    const float* __restrict__ cw, const float* __restrict__ cb,
    const float* __restrict__ xpw, const float* __restrict__ dpw, const float* __restrict__ dpb,
    const float* __restrict__ Alog,
    float* __restrict__ z_g, float* __restrict__ u_g, float* __restrict__ dl_g,
    float* __restrict__ B_g, float* __restrict__ C_g,
    float* __restrict__ chH, float* __restrict__ dtsumG) {
  __shared__ __align__(16) float ush[16][128];
  __shared__ __align__(16) float dsh[16][128];
  __shared__ __align__(16) float dbl[16][40];
  __shared__ __align__(16) char poolU[36 * 132 * 4];   // wsh[36][132] | (hts[19][64] + xpsh[19][128])
  float* hts  = (float*)poolU;            // [19][64]
  float* xpsh = hts + 19 * 64;            // [19][128]
  float* wsh  = (float*)poolU;            // [36][132] (after conv)

  const int t = threadIdx.x;
  const int c = blockIdx.x;          // chunk 0..255
  const int b = blockIdx.y;          // batch 0..3
  const int grow0 = b * SL + c * CT;

  // stage h rows [grow0-3, grow0+16); zero halo at sequence start
  for (int i = t; i < 19 * 64; i += 256) {
    int r = i >> 6, k = i & 63;
    float v = 0.f;
    if (!(c == 0 && r < 3)) v = h[(size_t)(grow0 - 3 + r) * 64 + k];
    hts[i] = v;
  }
  __syncthreads();

  // in_proj GEMM: thread = output col (0..255), 19 rows, K=64. ipwT loads coalesced.
  {
    const int cc = t;
    float acc[19];
#pragma unroll
    for (int r = 0; r < 19; ++r) acc[r] = 0.f;
    for (int k = 0; k < 64; k += 4) {
      float w0 = ipwT[(k + 0) * 256 + cc];
      float w1 = ipwT[(k + 1) * 256 + cc];
      float w2 = ipwT[(k + 2) * 256 + cc];
      float w3 = ipwT[(k + 3) * 256 + cc];
#pragma unroll
      for (int r = 0; r < 19; ++r) {
        const float* hr = hts + r * 64 + k;     // LDS broadcast
        acc[r] = fmaf(hr[0], w0, acc[r]);
        acc[r] = fmaf(hr[1], w1, acc[r]);
        acc[r] = fmaf(hr[2], w2, acc[r]);
        acc[r] = fmaf(hr[3], w3, acc[r]);
      }
    }
    if (cc < 128) {                 // xp columns -> LDS only
#pragma unroll
      for (int r = 0; r < 19; ++r) xpsh[r * 128 + cc] = acc[r];
    } else {                        // z columns -> global (rows 3..18 are real)
#pragma unroll
      for (int r = 3; r < 19; ++r)
        z_g[(size_t)(grow0 + r - 3) * 128 + (cc - 128)] = acc[r];
    }
  }
  __syncthreads();

  // conv + silu -> u (xpsh rows r..r+3 map to l-3..l)
  for (int i = t; i < 16 * 128; i += 256) {
    int r = i >> 7, dd = i & 127;
    float4 cwv = *(const float4*)(cw + dd * 4);
    float acc = cb[dd] + xpsh[(r + 0) * 128 + dd] * cwv.x + xpsh[(r + 1) * 128 + dd] * cwv.y +
                xpsh[(r + 2) * 128 + dd] * cwv.z + xpsh[(r + 3) * 128 + dd] * cwv.w;
    float uu = siluf(acc);
    ush[r][dd] = uu;
    u_g[(size_t)(grow0 + r) * 128 + dd] = uu;
  }
  __syncthreads();   // xpsh/hts dead

  // stage x_proj_w into wsh (overlays hts/xpsh)
  for (int i = t; i < 36 * 128; i += 256) {
    int cc = i >> 7, dd = i & 127;
    wsh[cc * 132 + dd] = xpw[cc * 128 + dd];
  }
  __syncthreads();

  // x_proj -> dbl[16][36]
  if (t < 144) {
    int r = t / 9, cg = t - (t / 9) * 9;
    int cc = cg * 4;
    float a0 = 0, a1 = 0, a2 = 0, a3 = 0;
#pragma unroll 8
    for (int k4 = 0; k4 < 32; ++k4) {
      float4 uu = *(const float4*)&ush[r][4 * k4];
      float4 w0 = *(const float4*)&wsh[(cc + 0) * 132 + 4 * k4];
      float4 w1 = *(const float4*)&wsh[(cc + 1) * 132 + 4 * k4];
      float4 w2 = *(const float4*)&wsh[(cc + 2) * 132 + 4 * k4];
      float4 w3 = *(const float4*)&wsh[(cc + 3) * 132 + 4 * k4];
      a0 += uu.x * w0.x + uu.y * w0.y + uu.z * w0.z + uu.w * w0.w;
      a1 += uu.x * w1.x + uu.y * w1.y + uu.z * w1.z + uu.w * w1.w;
      a2 += uu.x * w2.x + uu.y * w2.y + uu.z * w2.z + uu.w * w2.w;
      a3 += uu.x * w3.x + uu.y * w3.y + uu.z * w3.z + uu.w * w3.w;
    }
    dbl[r][cc + 0] = a0; dbl[r][cc + 1] = a1; dbl[r][cc + 2] = a2; dbl[r][cc + 3] = a3;
  }
  __syncthreads();

  // dt_proj + softplus -> delta; export delta + B/C
  for (int i = t; i < 16 * 128; i += 256) {
    int r = i >> 7, dd = i & 127;
    float4 wv = *(const float4*)(dpw + dd * 4);
    float acc = dpb[dd] + dbl[r][0] * wv.x + dbl[r][1] * wv.y + dbl[r][2] * wv.z + dbl[r][3] * wv.w;
    float dt = softplusf(acc);
    dsh[r][dd] = dt;
    dl_g[(size_t)(grow0 + r) * 128 + dd] = dt;
  }
  for (int i = t; i < 16 * 32; i += 256) {
    int r = i >> 5, j = i & 31;
    float v = dbl[r][4 + j];
    if (j < 16) B_g[(grow0 + r) * 16 + j] = v;
    else        C_g[(grow0 + r) * 16 + (j - 16)] = v;
  }
  __syncthreads();

  // chunk-local scan (thread = (d, half); 8 states each)
  {
    const int d = t & 127, hf = t >> 7, n0 = hf * 8;
    float a[8], hst[8];
#pragma unroll
    for (int j = 0; j < 8; ++j) {
      a[j] = -__expf(Alog[d * 16 + n0 + j]);
      hst[j] = 0.f;
    }
    float dts = 0.f;
#pragma unroll 4
    for (int tt = 0; tt < CT; ++tt) {
      float dt = dsh[tt][d];
      float du = dt * ush[tt][d];
      dts += dt;
#pragma unroll
      for (int j = 0; j < 8; ++j) {
        float e = __expf(dt * a[j]);
        hst[j] = fmaf(e, hst[j], du * dbl[tt][4 + n0 + j]);
      }
    }
    size_t off = ((size_t)(b * NC + c) * 128 + d) * 16 + n0;
    *(float4*)(chH + off + 0) = make_float4(hst[0], hst[1], hst[2], hst[3]);
    *(float4*)(chH + off + 4) = make_float4(hst[4], hst[5], hst[6], hst[7]);
    if (hf == 0) dtsumG[(b * NC + c) * 128 + d] = dts;
  }
}

// ---------------- scan2p: two-level carry propagation, block per (b,d) ----------------
__global__ __launch_bounds__(256) void k_scan2p(const float* __restrict__ Alog,
                                                const float* __restrict__ dtsumG, float* chH) {
  __shared__ float sP[16][16];
  __shared__ float sH[16][16];
  const int t = threadIdx.x;
  const int n = t & 15, g = t >> 4;
  const int d = blockIdx.x, b = blockIdx.y;
  const float A2 = -__expf(Alog[d * 16 + n]);

  float el[16], Hl[16];
  float cp = 1.f, ch = 0.f;
#pragma unroll
  for (int i = 0; i < 16; ++i) {
    int cc = g * 16 + i;
    float ds = dtsumG[(b * NC + cc) * 128 + d];
    float e = __expf(ds * A2);
    float H = chH[((size_t)(b * NC + cc) * 128 + d) * 16 + n];
    el[i] = e; Hl[i] = H;
    ch = fmaf(e, ch, H);
    cp *= e;
  }
  sP[g][n] = cp; sH[g][n] = ch;
  __syncthreads();
#pragma unroll
  for (int s = 1; s < 16; s <<= 1) {
    float pL = 1.f, hL = 0.f;
    if (g >= s) { pL = sP[g - s][n]; hL = sH[g - s][n]; }
    __syncthreads();
    ch = fmaf(cp, hL, ch);
    cp = cp * pL;
    sP[g][n] = cp; sH[g][n] = ch;
    __syncthreads();
  }
  float carry = 0.f;
  if (g > 0) carry = sH[g - 1][n];
#pragma unroll
  for (int i = 0; i < 16; ++i) {
    size_t idx = ((size_t)(b * NC + g * 16 + i) * 128 + d) * 16 + n;
    chH[idx] = carry;
    carry = fmaf(el[i], carry, Hl[i]);
  }
}

// ---------------- k_back: replay + gate + out_proj(opwT) + residual + pool(last) -------------
// r6-proven body; LDS 29.1KB -> 5 blocks/CU.
__global__ __launch_bounds__(256, 5) void k_back(const float* __restrict__ u_g, const float* __restrict__ dl_g,
                                                 const float* __restrict__ B_g, const float* __restrict__ C_g,
                                                 const float* __restrict__ z_g, const float* __restrict__ cin,
                                                 const float* __restrict__ Alog, const float* __restrict__ Dsk,
                                                 const float* __restrict__ opwT, float* __restrict__ h,
                                                 float* __restrict__ pool, int doPool) {
  __shared__ __align__(16) float ush[16][132];
  __shared__ __align__(16) float dsh[16][132];
  __shared__ float bsh[16][16];
  __shared__ float csh[16][16];
  __shared__ __align__(16) float ygsh[128][20];

  const int t = threadIdx.x;
  const int c = blockIdx.x;
  const int b = blockIdx.y;
  const int grow0 = b * SL + c * CT;

  for (int i = t; i < 16 * 128; i += 256) {
    int r = i >> 7, dd = i & 127;
    ush[r][dd] = u_g[(size_t)(grow0 + r) * 128 + dd];
    dsh[r][dd] = dl_g[(size_t)(grow0 + r) * 128 + dd];
  }
  for (int i = t; i < 16 * 32; i += 256) {
    int r = i >> 5, j = i & 31;
    if (j < 16) bsh[r][j] = B_g[(grow0 + r) * 16 + j];
    else        csh[r][j - 16] = C_g[(grow0 + r) * 16 + (j - 16)];
  }
  __syncthreads();

  // replay scan + D-skip + silu(z) gate; lane pair (d = t>>1, hf = t&1)
  {
    const int d = t >> 1, hf = t & 1, n0 = hf * 8;
    float a[8], hst[8];
    size_t off = ((size_t)(b * NC + c) * 128 + d) * 16 + n0;
    float4 h0 = *(const float4*)(cin + off + 0);
    float4 h1 = *(const float4*)(cin + off + 4);
    hst[0] = h0.x; hst[1] = h0.y; hst[2] = h0.z; hst[3] = h0.w;
    hst[4] = h1.x; hst[5] = h1.y; hst[6] = h1.z; hst[7] = h1.w;
#pragma unroll
    for (int j = 0; j < 8; ++j) a[j] = -__expf(Alog[d * 16 + n0 + j]);
    const float Dd = Dsk[d];
#pragma unroll 4
    for (int tt = 0; tt < CT; ++tt) {
      float dt = dsh[tt][d];
      float ut = ush[tt][d];
      float du = dt * ut;
      float yv = 0.f;
#pragma unroll
      for (int j = 0; j < 8; ++j) {
        float e = __expf(dt * a[j]);
        hst[j] = fmaf(e, hst[j], du * bsh[tt][n0 + j]);
        yv = fmaf(hst[j], csh[tt][n0 + j], yv);
      }
      float tot = yv + __shfl_xor(yv, 1);
      if (hf == 0) {
        float y = tot + ut * Dd;
        float zv = z_g[(size_t)(grow0 + tt) * 128 + d];
        ygsh[d][tt] = y * siluf(zv);
      }
    }
  }
  __syncthreads();

  // out_proj full-K per thread (opwT coalesced) + residual (+pool on last layer)
  {
    const int o = t & 63, q = t >> 6;
    float acc0 = 0.f, acc1 = 0.f, acc2 = 0.f, acc3 = 0.f;
#pragma unroll 8
    for (int k = 0; k < 128; ++k) {
      float w = opwT[k * 64 + o];
      float4 yv = *(const float4*)&ygsh[k][q * 4];
      acc0 = fmaf(yv.x, w, acc0);
      acc1 = fmaf(yv.y, w, acc1);
      acc2 = fmaf(yv.z, w, acc2);
      acc3 = fmaf(yv.w, w, acc3);
    }
    size_t row = (size_t)(grow0 + q * 4) * 64 + o;
    float h0 = h[row + 0 * 64] + acc0;
    float h1 = h[row + 1 * 64] + acc1;
    float h2 = h[row + 2 * 64] + acc2;
    float h3 = h[row + 3 * 64] + acc3;
    h[row + 0 * 64] = h0; h[row + 1 * 64] = h1;
    h[row + 2 * 64] = h2; h[row + 3 * 64] = h3;
    if (doPool) atomicAdd(pool + b * 64 + o, h0 + h1 + h2 + h3);
  }
}

// ---------------- classifier from pooled sums ----------------
__global__ __launch_bounds__(64) void k_cls(const float* __restrict__ pool, const float* __restrict__ wc,
                                            const float* __restrict__ bc, float* __restrict__ out) {
  const int t = threadIdx.x;
  if (t < 24) {
    int bb = t / 6, o = t - bb * 6;
    float acc = 0.f;
    for (int d2 = 0; d2 < 64; ++d2) acc += pool[bb * 64 + d2] * wc[o * 64 + d2];
    out[bb * 6 + o] = bc[o] + acc * (1.f / 4096.f);
  }
}

extern "C" void kernel_launch(void* const* d_in, const int* in_sizes, int n_in,
                              void* d_out, int out_size, void* d_ws, size_t ws_size,
                              hipStream_t stream) {
  const float* x    = (const float*)d_in[0];
  const float* w_in = (const float*)d_in[1];
  const float* b_in = (const float*)d_in[2];
  const float* ipw  = (const float*)d_in[3];
  const float* cw   = (const float*)d_in[4];
  const float* cb   = (const float*)d_in[5];
  const float* xpw  = (const float*)d_in[6];
  const float* dpw  = (const float*)d_in[7];
  const float* dpb  = (const float*)d_in[8];
  const float* Alog = (const float*)d_in[9];
  const float* Dsk  = (const float*)d_in[10];
  const float* opw  = (const float*)d_in[11];
  const float* wc   = (const float*)d_in[12];
  const float* bc   = (const float*)d_in[13];
  float* out = (float*)d_out;

  float* ws    = (float*)d_ws;
  float* h     = ws;                    // 1048576
  float* zb    = h + 1048576;           // 2097152
  float* ub    = zb + 2097152;          // 2097152
  float* dl    = ub + 2097152;          // 2097152
  float* Bb    = dl + 2097152;          // 262144
  float* Cb    = Bb + 262144;           // 262144
  float* chH   = Cb + 262144;           // 2097152 (Hl -> carry-in in place)
  float* dtsum = chH + 2097152;         // 131072
  float* ipwT  = dtsum + 131072;        // 32768
  float* opwT  = ipwT + 32768;          // 16384
  float* pool  = opwT + 16384;          // 256 (zeroed by k_linin)

  k_linin<<<256, 256, 0, stream>>>(x, w_in, b_in, ipw, opw, h, ipwT, opwT, pool);
  for (int i = 0; i < 2; ++i) {
    k_mid_ip<<<dim3(NC, 4), 256, 0, stream>>>(h, ipwT + i * 16384,
                                              cw + i * 512, cb + i * 128,
                                              xpw + i * 4608, dpw + i * 512, dpb + i * 128,
                                              Alog + i * 2048,
                                              zb, ub, dl, Bb, Cb, chH, dtsum);
    k_scan2p<<<dim3(128, 4), 256, 0, stream>>>(Alog + i * 2048, dtsum, chH);
    k_back<<<dim3(NC, 4), 256, 0, stream>>>(ub, dl, Bb, Cb, zb, chH,
                                            Alog + i * 2048, Dsk + i * 128,
                                            opwT + i * 8192, h, pool, i == 1 ? 1 : 0);
  }
  k_cls<<<1, 64, 0, stream>>>(pool, wc, bc, out);
}

// Round 10
// 263.295 us; speedup vs baseline: 1.2994x; 1.0303x over previous
//
#include <hip/hip_runtime.h>

// TinyMambaMulti: B=4, L=4096, D_MODEL=64, D_INNER=128, D_STATE=16, DT_RANK=4,
// D_CONV=4, N_LAYERS=2, OUT=6. All fp32.
// r6 skeleton (best: 246.7us), 11 dispatches:
//   linin -> [inproj, mid, scan2p, back]x2 -> poolpart -> cls
// Deltas vs r6: (1) k_mid publishes dtsum (chP eliminated; P=exp(dtsum*A) recomputed
// in scan2p — bit-identical), coalesced chH [b][c][d][n]; (2) k_back keeps y in
// fully-unrolled regs, ygsh overlays dsh/bsh/csh -> LDS 18.9KB, (256,6).
// Lessons ledger: r5 coop mega-fusion loses (spill+2blk/CU); r7 don't unstage
// inner-loop operands / don't squeeze VGPR; r8 no GEMM in k_back tail; r9 inproj
// fusion is a wash.

#define NB 4
#define SL 4096
#define NC 256           // scan chunks per sequence
#define CT 16            // steps per chunk (NC*CT == SL)

__device__ __forceinline__ float siluf(float x) { return x / (1.f + __expf(-x)); }
__device__ __forceinline__ float softplusf(float x) { return x > 20.f ? x : log1pf(__expf(x)); }

// ---------------- linear_in: h[r][64] = x[r][57] @ w[64][57]^T + b ----------------
__global__ __launch_bounds__(256) void k_linin(const float* __restrict__ x, const float* __restrict__ w,
                                               const float* __restrict__ bias, float* __restrict__ h) {
  __shared__ __align__(16) float xs[64][60];
  __shared__ __align__(16) float ws[64][60];
  const int t = threadIdx.x;
  const int r0 = blockIdx.x * 64;
  for (int i = t; i < 64 * 57; i += 256) {
    int r = i / 57, k = i - r * 57;
    xs[r][k] = x[(r0 + r) * 57 + k];
    ws[r][k] = w[i];
  }
  for (int i = t; i < 64 * 3; i += 256) {
    int r = i / 3, j = i - r * 3;
    xs[r][57 + j] = 0.f;
    ws[r][57 + j] = 0.f;
  }
  __syncthreads();
  const int col = t & 63;
  const int rg = t >> 6;
  float wreg[15][4];
#pragma unroll
  for (int k4 = 0; k4 < 15; ++k4) {
    float4 v = *(const float4*)&ws[col][k4 * 4];
    wreg[k4][0] = v.x; wreg[k4][1] = v.y; wreg[k4][2] = v.z; wreg[k4][3] = v.w;
  }
  const float bcol = bias[col];
  for (int g = 0; g < 4; ++g) {
    const int rb = rg * 16 + g * 4;
    float acc[4] = {bcol, bcol, bcol, bcol};
#pragma unroll
    for (int k4 = 0; k4 < 15; ++k4) {
#pragma unroll
      for (int i = 0; i < 4; ++i) {
        float4 xv = *(const float4*)&xs[rb + i][k4 * 4];
        acc[i] = fmaf(xv.x, wreg[k4][0], acc[i]);
        acc[i] = fmaf(xv.y, wreg[k4][1], acc[i]);
        acc[i] = fmaf(xv.z, wreg[k4][2], acc[i]);
        acc[i] = fmaf(xv.w, wreg[k4][3], acc[i]);
      }
    }
#pragma unroll
    for (int i = 0; i < 4; ++i) h[(r0 + rb + i) * 64 + col] = acc[i];
  }
}

// ---------------- in_proj: [16384x256] = h[16384x64] @ W[256x64]^T, split xp/z ----------------
__global__ __launch_bounds__(256) void k_inproj(const float* __restrict__ hin, const float* __restrict__ W,
                                                float* __restrict__ xp, float* __restrict__ z) {
  __shared__ __align__(16) float ht[64][68];
  __shared__ __align__(16) float wt[64][68];
  const int t = threadIdx.x;
  const int r0 = blockIdx.x * 64;
  const int c0 = blockIdx.y * 64;
  for (int idx = t; idx < 64 * 16; idx += 256) {
    int r = idx >> 4, k4 = idx & 15;
    float4 v = *(const float4*)(hin + (r0 + r) * 64 + 4 * k4);
    ht[4 * k4 + 0][r] = v.x; ht[4 * k4 + 1][r] = v.y; ht[4 * k4 + 2][r] = v.z; ht[4 * k4 + 3][r] = v.w;
  }
  for (int idx = t; idx < 64 * 16; idx += 256) {
    int c = idx >> 4, k4 = idx & 15;
    float4 v = *(const float4*)(W + (c0 + c) * 64 + 4 * k4);
    wt[4 * k4 + 0][c] = v.x; wt[4 * k4 + 1][c] = v.y; wt[4 * k4 + 2][c] = v.z; wt[4 * k4 + 3][c] = v.w;
  }
  __syncthreads();
  const int tc = t & 15, tr = t >> 4;
  float acc[4][4] = {};
  for (int k = 0; k < 64; ++k) {
    float4 a = *(const float4*)&ht[k][4 * tr];
    float4 b = *(const float4*)&wt[k][4 * tc];
    float av[4] = {a.x, a.y, a.z, a.w};
    float bv[4] = {b.x, b.y, b.z, b.w};
#pragma unroll
    for (int i = 0; i < 4; ++i)
#pragma unroll
      for (int j = 0; j < 4; ++j) acc[i][j] = fmaf(av[i], bv[j], acc[i][j]);
  }
#pragma unroll
  for (int i = 0; i < 4; ++i) {
    int row = r0 + 4 * tr + i;
    int c = c0 + 4 * tc;
    float4 v = make_float4(acc[i][0], acc[i][1], acc[i][2], acc[i][3]);
    if (c0 < 128) *(float4*)(xp + row * 128 + c) = v;
    else          *(float4*)(z + row * 128 + (c - 128)) = v;
  }
}

// ---------------- K_mid: conv+silu + x_proj + dt_proj + chunk-local scan (r6 body) -----------
// LDS 38.5 KB -> 4 blocks/CU. Publishes Hl (coalesced [b][c][d][n]) + dtsum.
__global__ __launch_bounds__(256, 4) void k_mid(const float* __restrict__ xp, const float* __restrict__ cw,
                                                const float* __restrict__ cb, const float* __restrict__ xpw,
                                                const float* __restrict__ dpw, const float* __restrict__ dpb,
                                                const float* __restrict__ Alog,
                                                float* __restrict__ u_g, float* __restrict__ dl_g,
                                                float* __restrict__ B_g, float* __restrict__ C_g,
                                                float* __restrict__ chH, float* __restrict__ dtsumG) {
  __shared__ __align__(16) float ush[16][132];
  __shared__ __align__(16) float dsh[16][132];
  __shared__ __align__(16) float wsh[36][132];
  __shared__ __align__(16) float dbl[16][40];

  const int t = threadIdx.x;
  const int c = blockIdx.x;          // chunk 0..255
  const int b = blockIdx.y;          // batch 0..3
  const int grow0 = b * SL + c * CT;

  // stage x_proj_w (not read until after first sync)
  for (int i = t; i < 36 * 128; i += 256) {
    int cc = i >> 7, dd = i & 127;
    wsh[cc][dd] = xpw[cc * 128 + dd];
  }
  // conv + silu -> u (direct global reads; halo rows via pointer math)
  for (int i = t; i < 16 * 128; i += 256) {
    int r = i >> 7, dd = i & 127;
    float4 cwv = *(const float4*)(cw + dd * 4);
    const float* base = xp + (size_t)(grow0 + r) * 128 + dd;
    int l = c * CT + r;
    float acc = cb[dd] + base[0] * cwv.w;
    if (l >= 1) acc += base[-128] * cwv.z;
    if (l >= 2) acc += base[-256] * cwv.y;
    if (l >= 3) acc += base[-384] * cwv.x;
    float uu = siluf(acc);
    ush[r][dd] = uu;
    u_g[(size_t)(grow0 + r) * 128 + dd] = uu;
  }
  __syncthreads();

  // x_proj -> dbl[16][36]
  if (t < 144) {
    int r = t / 9, cg = t - (t / 9) * 9;
    int cc = cg * 4;
    float a0 = 0, a1 = 0, a2 = 0, a3 = 0;
#pragma unroll 8
    for (int k4 = 0; k4 < 32; ++k4) {
      float4 uu = *(const float4*)&ush[r][4 * k4];
      float4 w0 = *(const float4*)&wsh[cc + 0][4 * k4];
      float4 w1 = *(const float4*)&wsh[cc + 1][4 * k4];
      float4 w2 = *(const float4*)&wsh[cc + 2][4 * k4];
      float4 w3 = *(const float4*)&wsh[cc + 3][4 * k4];
      a0 += uu.x * w0.x + uu.y * w0.y + uu.z * w0.z + uu.w * w0.w;
      a1 += uu.x * w1.x + uu.y * w1.y + uu.z * w1.z + uu.w * w1.w;
      a2 += uu.x * w2.x + uu.y * w2.y + uu.z * w2.z + uu.w * w2.w;
      a3 += uu.x * w3.x + uu.y * w3.y + uu.z * w3.z + uu.w * w3.w;
    }
    dbl[r][cc + 0] = a0; dbl[r][cc + 1] = a1; dbl[r][cc + 2] = a2; dbl[r][cc + 3] = a3;
  }
  __syncthreads();

  // dt_proj + softplus -> delta; export delta + B/C
  for (int i = t; i < 16 * 128; i += 256) {
    int r = i >> 7, dd = i & 127;
    float4 wv = *(const float4*)(dpw + dd * 4);
    float acc = dpb[dd] + dbl[r][0] * wv.x + dbl[r][1] * wv.y + dbl[r][2] * wv.z + dbl[r][3] * wv.w;
    float dt = softplusf(acc);
    dsh[r][dd] = dt;
    dl_g[(size_t)(grow0 + r) * 128 + dd] = dt;
  }
  for (int i = t; i < 16 * 32; i += 256) {
    int r = i >> 5, j = i & 31;
    float v = dbl[r][4 + j];
    if (j < 16) B_g[(grow0 + r) * 16 + j] = v;
    else        C_g[(grow0 + r) * 16 + (j - 16)] = v;
  }
  __syncthreads();

  // chunk-local scan (thread = (d, half); 8 states each)
  {
    const int d = t & 127, hf = t >> 7, n0 = hf * 8;
    float a[8], hst[8];
#pragma unroll
    for (int j = 0; j < 8; ++j) {
      a[j] = -__expf(Alog[d * 16 + n0 + j]);
      hst[j] = 0.f;
    }
    float dts = 0.f;
#pragma unroll 4
    for (int tt = 0; tt < CT; ++tt) {
      float dt = dsh[tt][d];
      float du = dt * ush[tt][d];
      dts += dt;
#pragma unroll
      for (int j = 0; j < 8; ++j) {
        float e = __expf(dt * a[j]);
        hst[j] = fmaf(e, hst[j], du * dbl[tt][4 + n0 + j]);
      }
    }
    size_t off = ((size_t)(b * NC + c) * 128 + d) * 16 + n0;   // coalesced [b][c][d][n]
    *(float4*)(chH + off + 0) = make_float4(hst[0], hst[1], hst[2], hst[3]);
    *(float4*)(chH + off + 4) = make_float4(hst[4], hst[5], hst[6], hst[7]);
    if (hf == 0) dtsumG[(b * NC + c) * 128 + d] = dts;
  }
}

// ---------------- scan2p: two-level carry propagation, block per (b,d) ----------------
// P recomputed from dtsum: P = exp(dtsum*A) (identical formula). In-place carry-in.
__global__ __launch_bounds__(256) void k_scan2p(const float* __restrict__ Alog,
                                                const float* __restrict__ dtsumG, float* chH) {
  __shared__ float sP[16][16];
  __shared__ float sH[16][16];
  const int t = threadIdx.x;
  const int n = t & 15, g = t >> 4;
  const int d = blockIdx.x, b = blockIdx.y;
  const float A2 = -__expf(Alog[d * 16 + n]);

  float el[16], Hl[16];
  float cp = 1.f, ch = 0.f;
#pragma unroll
  for (int i = 0; i < 16; ++i) {
    int cc = g * 16 + i;
    float ds = dtsumG[(b * NC + cc) * 128 + d];
    float e = __expf(ds * A2);
    float H = chH[((size_t)(b * NC + cc) * 128 + d) * 16 + n];
    el[i] = e; Hl[i] = H;
    ch = fmaf(e, ch, H);
    cp *= e;
  }
  sP[g][n] = cp; sH[g][n] = ch;
  __syncthreads();
#pragma unroll
  for (int s = 1; s < 16; s <<= 1) {
    float pL = 1.f, hL = 0.f;
    if (g >= s) { pL = sP[g - s][n]; hL = sH[g - s][n]; }
    __syncthreads();
    ch = fmaf(cp, hL, ch);
    cp = cp * pL;
    sP[g][n] = cp; sH[g][n] = ch;
    __syncthreads();
  }
  float carry = 0.f;
  if (g > 0) carry = sH[g - 1][n];
#pragma unroll
  for (int i = 0; i < 16; ++i) {
    size_t idx = ((size_t)(b * NC + g * 16 + i) * 128 + d) * 16 + n;
    chH[idx] = carry;
    carry = fmaf(el[i], carry, Hl[i]);
  }
}

// ---------------- K_back: replay + gate + out_proj(opw direct) + residual (r6 body) ----------
// Delta vs r6: y kept in fully-unrolled regs; ygsh overlays dsh/bsh/csh after the loop.
// LDS 18.9 KB; (256,6) -> 24 waves/CU.
__global__ __launch_bounds__(256, 6) void k_back(const float* __restrict__ u_g, const float* __restrict__ dl_g,
                                                 const float* __restrict__ B_g, const float* __restrict__ C_g,
                                                 const float* __restrict__ z_g, const float* __restrict__ cin,
                                                 const float* __restrict__ Alog, const float* __restrict__ Dsk,
                                                 const float* __restrict__ opw, float* __restrict__ h) {
  __shared__ __align__(16) float ush[16][132];                 // 8448 B (live through scan)
  __shared__ __align__(16) char poolB[10496];                  // dsh+bsh+csh | ygsh
  float* dsh  = (float*)poolB;          // [16][132]
  float* bsh  = dsh + 16 * 132;         // [16][16]
  float* csh  = bsh + 256;              // [16][16]
  float* ygsh = (float*)poolB;          // [128][20] after scan (10240 <= 10496)

  const int t = threadIdx.x;
  const int c = blockIdx.x;
  const int b = blockIdx.y;
  const int grow0 = b * SL + c * CT;

  for (int i = t; i < 16 * 128; i += 256) {
    int r = i >> 7, dd = i & 127;
    ush[r][dd] = u_g[(size_t)(grow0 + r) * 128 + dd];
    dsh[r * 132 + dd] = dl_g[(size_t)(grow0 + r) * 128 + dd];
  }
  for (int i = t; i < 16 * 32; i += 256) {
    int r = i >> 5, j = i & 31;
    if (j < 16) bsh[r * 16 + j] = B_g[(grow0 + r) * 16 + j];
    else        csh[r * 16 + (j - 16)] = C_g[(grow0 + r) * 16 + (j - 16)];
  }
  __syncthreads();

  // replay scan + D-skip + silu(z) gate; lane pair (d = t>>1, hf = t&1); y in regs
  const int d = t >> 1, hf = t & 1;
  float ytmp[CT];
  {
    const int n0 = hf * 8;
    float a[8], hst[8];
    size_t off = ((size_t)(b * NC + c) * 128 + d) * 16 + n0;
    float4 h0 = *(const float4*)(cin + off + 0);
    float4 h1 = *(const float4*)(cin + off + 4);
    hst[0] = h0.x; hst[1] = h0.y; hst[2] = h0.z; hst[3] = h0.w;
    hst[4] = h1.x; hst[5] = h1.y; hst[6] = h1.z; hst[7] = h1.w;
#pragma unroll
    for (int j = 0; j < 8; ++j) a[j] = -__expf(Alog[d * 16 + n0 + j]);
    const float Dd = Dsk[d];
#pragma unroll
    for (int tt = 0; tt < CT; ++tt) {    // FULL unroll: ytmp indices static
      float dt = dsh[tt * 132 + d];
      float ut = ush[tt][d];
      float du = dt * ut;
      float yv = 0.f;
#pragma unroll
      for (int j = 0; j < 8; ++j) {
        float e = __expf(dt * a[j]);
        hst[j] = fmaf(e, hst[j], du * bsh[tt * 16 + n0 + j]);
        yv = fmaf(hst[j], csh[tt * 16 + n0 + j], yv);
      }
      float tot = yv + __shfl_xor(yv, 1);
      float zv = z_g[(size_t)(grow0 + tt) * 128 + d];
      ytmp[tt] = (tot + ut * Dd) * siluf(zv);
    }
  }
  __syncthreads();   // all reads of dsh/bsh/csh done; safe to overlay with ygsh
  if (hf == 0) {
#pragma unroll
    for (int tt = 0; tt < CT; ++tt) ygsh[d * 20 + tt] = ytmp[tt];
  }
  __syncthreads();

  // out_proj full-K per thread (opw [64][128] direct, float4 over k) + residual
  {
    const int o = t & 63, q = t >> 6;     // rows q*4 .. q*4+3
    float acc0 = 0.f, acc1 = 0.f, acc2 = 0.f, acc3 = 0.f;
#pragma unroll 8
    for (int k4 = 0; k4 < 32; ++k4) {
      float4 w4 = *(const float4*)(opw + o * 128 + 4 * k4);
      float4 y0 = *(const float4*)&ygsh[(4 * k4 + 0) * 20 + q * 4];
      float4 y1 = *(const float4*)&ygsh[(4 * k4 + 1) * 20 + q * 4];
      float4 y2 = *(const float4*)&ygsh[(4 * k4 + 2) * 20 + q * 4];
      float4 y3 = *(const float4*)&ygsh[(4 * k4 + 3) * 20 + q * 4];
      acc0 = fmaf(y0.x, w4.x, acc0); acc0 = fmaf(y1.x, w4.y, acc0);
      acc0 = fmaf(y2.x, w4.z, acc0); acc0 = fmaf(y3.x, w4.w, acc0);
      acc1 = fmaf(y0.y, w4.x, acc1); acc1 = fmaf(y1.y, w4.y, acc1);
      acc1 = fmaf(y2.y, w4.z, acc1); acc1 = fmaf(y3.y, w4.w, acc1);
      acc2 = fmaf(y0.z, w4.x, acc2); acc2 = fmaf(y1.z, w4.y, acc2);
      acc2 = fmaf(y2.z, w4.z, acc2); acc2 = fmaf(y3.z, w4.w, acc2);
      acc3 = fmaf(y0.w, w4.x, acc3); acc3 = fmaf(y1.w, w4.y, acc3);
      acc3 = fmaf(y2.w, w4.z, acc3); acc3 = fmaf(y3.w, w4.w, acc3);
    }
    size_t row = (size_t)(grow0 + q * 4) * 64 + o;
    h[row + 0 * 64] += acc0;
    h[row + 1 * 64] += acc1;
    h[row + 2 * 64] += acc2;
    h[row + 3 * 64] += acc3;
  }
}

// ---------------- pooling partials over L ----------------
__global__ __launch_bounds__(256) void k_poolpart(const float* __restrict__ h, float* __restrict__ pp) {
  const int lb = blockIdx.x;
  const int b = blockIdx.y;
  const int t = threadIdx.x;
  const int d = t & 63, part = t >> 6;
  float s = 0.f;
  for (int i = 0; i < 32; ++i) {
    int l = lb * 128 + part + i * 4;
    s += h[(size_t)(b * SL + l) * 64 + d];
  }
  __shared__ float red[256];
  red[t] = s;
  __syncthreads();
  if (t < 64) pp[(b * 32 + lb) * 64 + t] = red[t] + red[t + 64] + red[t + 128] + red[t + 192];
}

// ---------------- final reduce + classifier ----------------
__global__ __launch_bounds__(256) void k_cls(const float* __restrict__ pp, const float* __restrict__ wc,
                                             const float* __restrict__ bc, float* __restrict__ out) {
  const int t = threadIdx.x;
  __shared__ float pooled[4][64];
  int b = t >> 6, d = t & 63;
  float s = 0.f;
  for (int lb = 0; lb < 32; ++lb) s += pp[(b * 32 + lb) * 64 + d];
  pooled[b][d] = s * (1.f / 4096.f);
  __syncthreads();
  if (t < 24) {
    int bb = t / 6, o = t - bb * 6;
    float acc = bc[o];
    for (int d2 = 0; d2 < 64; ++d2) acc += pooled[bb][d2] * wc[o * 64 + d2];
    out[bb * 6 + o] = acc;
  }
}

extern "C" void kernel_launch(void* const* d_in, const int* in_sizes, int n_in,
                              void* d_out, int out_size, void* d_ws, size_t ws_size,
                              hipStream_t stream) {
  const float* x    = (const float*)d_in[0];
  const float* w_in = (const float*)d_in[1];
  const float* b_in = (const float*)d_in[2];
  const float* ipw  = (const float*)d_in[3];
  const float* cw   = (const float*)d_in[4];
  const float* cb   = (const float*)d_in[5];
  const float* xpw  = (const float*)d_in[6];
  const float* dpw  = (const float*)d_in[7];
  const float* dpb  = (const float*)d_in[8];
  const float* Alog = (const float*)d_in[9];
  const float* Dsk  = (const float*)d_in[10];
  const float* opw  = (const float*)d_in[11];
  const float* wc   = (const float*)d_in[12];
  const float* bc   = (const float*)d_in[13];
  float* out = (float*)d_out;

  float* ws    = (float*)d_ws;
  float* h     = ws;                    // 1048576
  float* xp    = h + 1048576;           // 2097152
  float* zb    = xp + 2097152;          // 2097152
  float* ub    = zb + 2097152;          // 2097152
  float* dl    = ub + 2097152;          // 2097152
  float* Bb    = dl + 2097152;          // 262144
  float* Cb    = Bb + 262144;           // 262144
  float* chH   = Cb + 262144;           // 2097152 (Hl -> carry-in in place)
  float* dtsum = chH + 2097152;         // 131072
  float* pp    = dtsum + 131072;        // 8192

  k_linin<<<256, 256, 0, stream>>>(x, w_in, b_in, h);
  for (int i = 0; i < 2; ++i) {
    k_inproj<<<dim3(256, 4), 256, 0, stream>>>(h, ipw + i * 16384, xp, zb);
    k_mid<<<dim3(NC, 4), 256, 0, stream>>>(xp, cw + i * 512, cb + i * 128,
                                           xpw + i * 4608, dpw + i * 512, dpb + i * 128,
                                           Alog + i * 2048, ub, dl, Bb, Cb, chH, dtsum);
    k_scan2p<<<dim3(128, 4), 256, 0, stream>>>(Alog + i * 2048, dtsum, chH);
    k_back<<<dim3(NC, 4), 256, 0, stream>>>(ub, dl, Bb, Cb, zb, chH,
                                            Alog + i * 2048, Dsk + i * 128,
                                            opw + i * 8192, h);
  }
  k_poolpart<<<dim3(32, 4), 256, 0, stream>>>(h, pp);
  k_cls<<<1, 256, 0, stream>>>(pp, wc, bc, out);
}

// Round 11
// 255.503 us; speedup vs baseline: 1.3391x; 1.0305x over previous
//
#include <hip/hip_runtime.h>

// TinyMambaMulti: B=4, L=4096, D_MODEL=64, D_INNER=128, D_STATE=16, DT_RANK=4,
// D_CONV=4, N_LAYERS=2, OUT=6. All fp32.
// r6 skeleton (proven best 246.7us), 12 dispatches:
//   prep -> linin -> [inproj, mid, scan2p, back]x2 -> poolpart -> cls
// SINGLE delta vs r6: k_back is now a streaming kernel — no LDS staging of
// u/dl/B/C; all scan operands read directly from global inside the unrolled
// loop (independent addresses -> deep MLP). LDS = ygsh only (10.2KB), 1 barrier.
// Ledger: r5 coop fusion loses; r7 don't unstage *inner-GEMM* operands or squeeze
// VGPR; r8 no GEMM in back tail; r9 inproj fusion wash; r10 confounded deltas lose.
// Grid 1024 blocks caps residency at 4 blocks/CU — launch_bounds >4 buys nothing.

#define NB 4
#define SL 4096
#define NC 256           // scan chunks per sequence
#define CT 16            // steps per chunk (NC*CT == SL)

__device__ __forceinline__ float siluf(float x) { return x / (1.f + __expf(-x)); }
__device__ __forceinline__ float softplusf(float x) { return x > 20.f ? x : log1pf(__expf(x)); }

// ---------------- prep: transpose out_proj_w [2][64][128] -> opwT [2][128][64] ----------------
__global__ __launch_bounds__(256) void k_prep(const float* __restrict__ opw, float* __restrict__ opwT) {
  int i = blockIdx.x * 256 + threadIdx.x;   // 16384
  int l = i >> 13;
  int rem = i & 8191;
  int d = rem >> 6, m = rem & 63;
  opwT[i] = opw[l * 8192 + m * 128 + d];
}

// ---------------- linear_in: h[r][64] = x[r][57] @ w[64][57]^T + b ----------------
__global__ __launch_bounds__(256) void k_linin(const float* __restrict__ x, const float* __restrict__ w,
                                               const float* __restrict__ bias, float* __restrict__ h) {
  __shared__ __align__(16) float xs[64][60];
  __shared__ __align__(16) float ws[64][60];
  const int t = threadIdx.x;
  const int r0 = blockIdx.x * 64;
  for (int i = t; i < 64 * 57; i += 256) {
    int r = i / 57, k = i - r * 57;
    xs[r][k] = x[(r0 + r) * 57 + k];
    ws[r][k] = w[i];
  }
  for (int i = t; i < 64 * 3; i += 256) {
    int r = i / 3, j = i - r * 3;
    xs[r][57 + j] = 0.f;
    ws[r][57 + j] = 0.f;
  }
  __syncthreads();
  const int col = t & 63;
  const int rg = t >> 6;
  float wreg[15][4];
#pragma unroll
  for (int k4 = 0; k4 < 15; ++k4) {
    float4 v = *(const float4*)&ws[col][k4 * 4];
    wreg[k4][0] = v.x; wreg[k4][1] = v.y; wreg[k4][2] = v.z; wreg[k4][3] = v.w;
  }
  const float bcol = bias[col];
  for (int g = 0; g < 4; ++g) {
    const int rb = rg * 16 + g * 4;
    float acc[4] = {bcol, bcol, bcol, bcol};
#pragma unroll
    for (int k4 = 0; k4 < 15; ++k4) {
#pragma unroll
      for (int i = 0; i < 4; ++i) {
        float4 xv = *(const float4*)&xs[rb + i][k4 * 4];
        acc[i] = fmaf(xv.x, wreg[k4][0], acc[i]);
        acc[i] = fmaf(xv.y, wreg[k4][1], acc[i]);
        acc[i] = fmaf(xv.z, wreg[k4][2], acc[i]);
        acc[i] = fmaf(xv.w, wreg[k4][3], acc[i]);
      }
    }
#pragma unroll
    for (int i = 0; i < 4; ++i) h[(r0 + rb + i) * 64 + col] = acc[i];
  }
}

// ---------------- in_proj: [16384x256] = h[16384x64] @ W[256x64]^T, split xp/z ----------------
__global__ __launch_bounds__(256) void k_inproj(const float* __restrict__ hin, const float* __restrict__ W,
                                                float* __restrict__ xp, float* __restrict__ z) {
  __shared__ __align__(16) float ht[64][68];
  __shared__ __align__(16) float wt[64][68];
  const int t = threadIdx.x;
  const int r0 = blockIdx.x * 64;
  const int c0 = blockIdx.y * 64;
  for (int idx = t; idx < 64 * 16; idx += 256) {
    int r = idx >> 4, k4 = idx & 15;
    float4 v = *(const float4*)(hin + (r0 + r) * 64 + 4 * k4);
    ht[4 * k4 + 0][r] = v.x; ht[4 * k4 + 1][r] = v.y; ht[4 * k4 + 2][r] = v.z; ht[4 * k4 + 3][r] = v.w;
  }
  for (int idx = t; idx < 64 * 16; idx += 256) {
    int c = idx >> 4, k4 = idx & 15;
    float4 v = *(const float4*)(W + (c0 + c) * 64 + 4 * k4);
    wt[4 * k4 + 0][c] = v.x; wt[4 * k4 + 1][c] = v.y; wt[4 * k4 + 2][c] = v.z; wt[4 * k4 + 3][c] = v.w;
  }
  __syncthreads();
  const int tc = t & 15, tr = t >> 4;
  float acc[4][4] = {};
  for (int k = 0; k < 64; ++k) {
    float4 a = *(const float4*)&ht[k][4 * tr];
    float4 b = *(const float4*)&wt[k][4 * tc];
    float av[4] = {a.x, a.y, a.z, a.w};
    float bv[4] = {b.x, b.y, b.z, b.w};
#pragma unroll
    for (int i = 0; i < 4; ++i)
#pragma unroll
      for (int j = 0; j < 4; ++j) acc[i][j] = fmaf(av[i], bv[j], acc[i][j]);
  }
#pragma unroll
  for (int i = 0; i < 4; ++i) {
    int row = r0 + 4 * tr + i;
    int c = c0 + 4 * tc;
    float4 v = make_float4(acc[i][0], acc[i][1], acc[i][2], acc[i][3]);
    if (c0 < 128) *(float4*)(xp + row * 128 + c) = v;
    else          *(float4*)(z + row * 128 + (c - 128)) = v;
  }
}

// ---------------- K_mid: conv+silu + x_proj + dt_proj + chunk-local scan (r6 exact) ----------
__global__ __launch_bounds__(256, 4) void k_mid(const float* __restrict__ xp, const float* __restrict__ cw,
                                                const float* __restrict__ cb, const float* __restrict__ xpw,
                                                const float* __restrict__ dpw, const float* __restrict__ dpb,
                                                const float* __restrict__ Alog,
                                                float* __restrict__ u_g, float* __restrict__ dl_g,
                                                float* __restrict__ B_g, float* __restrict__ C_g,
                                                float* __restrict__ chP, float* __restrict__ chH) {
  __shared__ __align__(16) float ush[16][132];
  __shared__ __align__(16) float dsh[16][132];
  __shared__ __align__(16) float wsh[36][132];
  __shared__ __align__(16) float dbl[16][40];

  const int t = threadIdx.x;
  const int c = blockIdx.x;          // chunk 0..255
  const int b = blockIdx.y;          // batch 0..3
  const int grow0 = b * SL + c * CT;

  // stage x_proj_w (not read until after first sync)
  for (int i = t; i < 36 * 128; i += 256) {
    int cc = i >> 7, dd = i & 127;
    wsh[cc][dd] = xpw[cc * 128 + dd];
  }
  // conv + silu -> u (direct global reads; halo rows via pointer math)
  for (int i = t; i < 16 * 128; i += 256) {
    int r = i >> 7, dd = i & 127;
    float4 cwv = *(const float4*)(cw + dd * 4);
    const float* base = xp + (size_t)(grow0 + r) * 128 + dd;
    int l = c * CT + r;
    float acc = cb[dd] + base[0] * cwv.w;
    if (l >= 1) acc += base[-128] * cwv.z;
    if (l >= 2) acc += base[-256] * cwv.y;
    if (l >= 3) acc += base[-384] * cwv.x;
    float uu = siluf(acc);
    ush[r][dd] = uu;
    u_g[(size_t)(grow0 + r) * 128 + dd] = uu;
  }
  __syncthreads();

  // x_proj -> dbl[16][36]
  if (t < 144) {
    int r = t / 9, cg = t - (t / 9) * 9;
    int cc = cg * 4;
    float a0 = 0, a1 = 0, a2 = 0, a3 = 0;
#pragma unroll 8
    for (int k4 = 0; k4 < 32; ++k4) {
      float4 uu = *(const float4*)&ush[r][4 * k4];
      float4 w0 = *(const float4*)&wsh[cc + 0][4 * k4];
      float4 w1 = *(const float4*)&wsh[cc + 1][4 * k4];
      float4 w2 = *(const float4*)&wsh[cc + 2][4 * k4];
      float4 w3 = *(const float4*)&wsh[cc + 3][4 * k4];
      a0 += uu.x * w0.x + uu.y * w0.y + uu.z * w0.z + uu.w * w0.w;
      a1 += uu.x * w1.x + uu.y * w1.y + uu.z * w1.z + uu.w * w1.w;
      a2 += uu.x * w2.x + uu.y * w2.y + uu.z * w2.z + uu.w * w2.w;
      a3 += uu.x * w3.x + uu.y * w3.y + uu.z * w3.z + uu.w * w3.w;
    }
    dbl[r][cc + 0] = a0; dbl[r][cc + 1] = a1; dbl[r][cc + 2] = a2; dbl[r][cc + 3] = a3;
  }
  __syncthreads();

  // dt_proj + softplus -> delta; export delta + B/C
  for (int i = t; i < 16 * 128; i += 256) {
    int r = i >> 7, dd = i & 127;
    float4 wv = *(const float4*)(dpw + dd * 4);
    float acc = dpb[dd] + dbl[r][0] * wv.x + dbl[r][1] * wv.y + dbl[r][2] * wv.z + dbl[r][3] * wv.w;
    float dt = softplusf(acc);
    dsh[r][dd] = dt;
    dl_g[(size_t)(grow0 + r) * 128 + dd] = dt;
  }
  for (int i = t; i < 16 * 32; i += 256) {
    int r = i >> 5, j = i & 31;
    float v = dbl[r][4 + j];
    if (j < 16) B_g[(grow0 + r) * 16 + j] = v;
    else        C_g[(grow0 + r) * 16 + (j - 16)] = v;
  }
  __syncthreads();

  // chunk-local scan (thread = (d, half); 8 states each)
  {
    const int d = t & 127, hf = t >> 7, n0 = hf * 8;
    float a[8], hst[8];
#pragma unroll
    for (int j = 0; j < 8; ++j) {
      a[j] = -__expf(Alog[d * 16 + n0 + j]);
      hst[j] = 0.f;
    }
    float dts = 0.f;
#pragma unroll 4
    for (int tt = 0; tt < CT; ++tt) {
      float dt = dsh[tt][d];
      float du = dt * ush[tt][d];
      dts += dt;
#pragma unroll
      for (int j = 0; j < 8; ++j) {
        float e = __expf(dt * a[j]);
        hst[j] = fmaf(e, hst[j], du * dbl[tt][4 + n0 + j]);
      }
    }
    int off = ((b * 128 + d) * NC + c) * 16 + n0;
    float p[8];
#pragma unroll
    for (int j = 0; j < 8; ++j) p[j] = __expf(dts * a[j]);   // prod_t exp(dt*A) = exp(A*sum dt)
    *(float4*)(chP + off + 0) = make_float4(p[0], p[1], p[2], p[3]);
    *(float4*)(chP + off + 4) = make_float4(p[4], p[5], p[6], p[7]);
    *(float4*)(chH + off + 0) = make_float4(hst[0], hst[1], hst[2], hst[3]);
    *(float4*)(chH + off + 4) = make_float4(hst[4], hst[5], hst[6], hst[7]);
  }
}

// ---------------- scan2p: two-level carry propagation, block per (b,d) (r6 exact) ------------
__global__ __launch_bounds__(256) void k_scan2p(const float* __restrict__ chP, float* chH) {
  __shared__ float sP[16][16];   // [g][n]
  __shared__ float sH[16][16];
  const int t = threadIdx.x;
  const int n = t & 15, g = t >> 4;
  const int d = blockIdx.x, b = blockIdx.y;
  const int base = ((b * 128 + d) * NC) * 16 + n;

  float Pl[16], Hl[16];
  float cp = 1.f, ch = 0.f;
#pragma unroll
  for (int i = 0; i < 16; ++i) {
    int idx = base + (g * 16 + i) * 16;
    float P = chP[idx];
    float H = chH[idx];
    Pl[i] = P; Hl[i] = H;
    ch = fmaf(P, ch, H);
    cp *= P;
  }
  sP[g][n] = cp; sH[g][n] = ch;
  __syncthreads();
#pragma unroll
  for (int s = 1; s < 16; s <<= 1) {
    float pL = 1.f, hL = 0.f;
    if (g >= s) { pL = sP[g - s][n]; hL = sH[g - s][n]; }
    __syncthreads();
    ch = fmaf(cp, hL, ch);
    cp = cp * pL;
    sP[g][n] = cp; sH[g][n] = ch;
    __syncthreads();
  }
  float carry = 0.f;
  if (g > 0) carry = sH[g - 1][n];
#pragma unroll
  for (int i = 0; i < 16; ++i) {
    int idx = base + (g * 16 + i) * 16;
    chH[idx] = carry;
    carry = fmaf(Pl[i], carry, Hl[i]);
  }
}

// ---------------- K_back: STREAMING replay + gate + out_proj(opwT) + residual ----------------
// No input staging: u/dl/z lane-pair-coalesced global reads, B/C wave-broadcast reads,
// all loop loads address-independent of scan state -> deep MLP. LDS = ygsh only (10.2KB).
__global__ __launch_bounds__(256, 4) void k_back(const float* __restrict__ u_g, const float* __restrict__ dl_g,
                                                 const float* __restrict__ B_g, const float* __restrict__ C_g,
                                                 const float* __restrict__ z_g, const float* __restrict__ cin,
                                                 const float* __restrict__ Alog, const float* __restrict__ Dsk,
                                                 const float* __restrict__ opwT, float* __restrict__ h) {
  __shared__ __align__(16) float ygsh[128][20];
  const int t = threadIdx.x;
  const int c = blockIdx.x;
  const int b = blockIdx.y;
  const int grow0 = b * SL + c * CT;
  const int d = t >> 1, hf = t & 1, n0 = hf * 8;

  float a[8], hst[8];
  {
    size_t off = ((size_t)(b * 128 + d) * NC + c) * 16 + n0;
    float4 h0 = *(const float4*)(cin + off + 0);
    float4 h1 = *(const float4*)(cin + off + 4);
    hst[0] = h0.x; hst[1] = h0.y; hst[2] = h0.z; hst[3] = h0.w;
    hst[4] = h1.x; hst[5] = h1.y; hst[6] = h1.z; hst[7] = h1.w;
  }
#pragma unroll
  for (int j = 0; j < 8; ++j) a[j] = -__expf(Alog[d * 16 + n0 + j]);
  const float Dd = Dsk[d];

#pragma unroll
  for (int tt = 0; tt < CT; ++tt) {
    size_t row = (size_t)(grow0 + tt);
    float dt = dl_g[row * 128 + d];
    float ut = u_g[row * 128 + d];
    float zv = z_g[row * 128 + d];
    float4 Bv0 = *(const float4*)(B_g + row * 16 + n0);
    float4 Bv1 = *(const float4*)(B_g + row * 16 + n0 + 4);
    float4 Cv0 = *(const float4*)(C_g + row * 16 + n0);
    float4 Cv1 = *(const float4*)(C_g + row * 16 + n0 + 4);
    float Bv[8] = {Bv0.x, Bv0.y, Bv0.z, Bv0.w, Bv1.x, Bv1.y, Bv1.z, Bv1.w};
    float Cv[8] = {Cv0.x, Cv0.y, Cv0.z, Cv0.w, Cv1.x, Cv1.y, Cv1.z, Cv1.w};
    float du = dt * ut;
    float yv = 0.f;
#pragma unroll
    for (int j = 0; j < 8; ++j) {
      float e = __expf(dt * a[j]);
      hst[j] = fmaf(e, hst[j], du * Bv[j]);
      yv = fmaf(hst[j], Cv[j], yv);
    }
    float tot = yv + __shfl_xor(yv, 1);
    if (hf == 0) ygsh[d][tt] = (tot + ut * Dd) * siluf(zv);
  }
  __syncthreads();

  // out_proj full-K per thread (opwT coalesced) + residual
  {
    const int o = t & 63, q = t >> 6;
    float acc0 = 0.f, acc1 = 0.f, acc2 = 0.f, acc3 = 0.f;
#pragma unroll 8
    for (int k = 0; k < 128; ++k) {
      float w = opwT[k * 64 + o];
      float4 yv = *(const float4*)&ygsh[k][q * 4];
      acc0 = fmaf(yv.x, w, acc0);
      acc1 = fmaf(yv.y, w, acc1);
      acc2 = fmaf(yv.z, w, acc2);
      acc3 = fmaf(yv.w, w, acc3);
    }
    size_t row = (size_t)(grow0 + q * 4) * 64 + o;
    h[row + 0 * 64] += acc0;
    h[row + 1 * 64] += acc1;
    h[row + 2 * 64] += acc2;
    h[row + 3 * 64] += acc3;
  }
}

// ---------------- pooling partials over L ----------------
__global__ __launch_bounds__(256) void k_poolpart(const float* __restrict__ h, float* __restrict__ pp) {
  const int lb = blockIdx.x;
  const int b = blockIdx.y;
  const int t = threadIdx.x;
  const int d = t & 63, part = t >> 6;
  float s = 0.f;
  for (int i = 0; i < 32; ++i) {
    int l = lb * 128 + part + i * 4;
    s += h[(size_t)(b * SL + l) * 64 + d];
  }
  __shared__ float red[256];
  red[t] = s;
  __syncthreads();
  if (t < 64) pp[(b * 32 + lb) * 64 + t] = red[t] + red[t + 64] + red[t + 128] + red[t + 192];
}

// ---------------- final reduce + classifier ----------------
__global__ __launch_bounds__(256) void k_cls(const float* __restrict__ pp, const float* __restrict__ wc,
                                             const float* __restrict__ bc, float* __restrict__ out) {
  const int t = threadIdx.x;
  __shared__ float pooled[4][64];
  int b = t >> 6, d = t & 63;
  float s = 0.f;
  for (int lb = 0; lb < 32; ++lb) s += pp[(b * 32 + lb) * 64 + d];
  pooled[b][d] = s * (1.f / 4096.f);
  __syncthreads();
  if (t < 24) {
    int bb = t / 6, o = t - bb * 6;
    float acc = bc[o];
    for (int d2 = 0; d2 < 64; ++d2) acc += pooled[bb][d2] * wc[o * 64 + d2];
    out[bb * 6 + o] = acc;
  }
}

extern "C" void kernel_launch(void* const* d_in, const int* in_sizes, int n_in,
                              void* d_out, int out_size, void* d_ws, size_t ws_size,
                              hipStream_t stream) {
  const float* x    = (const float*)d_in[0];
  const float* w_in = (const float*)d_in[1];
  const float* b_in = (const float*)d_in[2];
  const float* ipw  = (const float*)d_in[3];
  const float* cw   = (const float*)d_in[4];
  const float* cb   = (const float*)d_in[5];
  const float* xpw  = (const float*)d_in[6];
  const float* dpw  = (const float*)d_in[7];
  const float* dpb  = (const float*)d_in[8];
  const float* Alog = (const float*)d_in[9];
  const float* Dsk  = (const float*)d_in[10];
  const float* opw  = (const float*)d_in[11];
  const float* wc   = (const float*)d_in[12];
  const float* bc   = (const float*)d_in[13];
  float* out = (float*)d_out;

  float* ws   = (float*)d_ws;
  float* h    = ws;                    // 1048576
  float* xp   = h + 1048576;           // 2097152
  float* zb   = xp + 2097152;          // 2097152
  float* ub   = zb + 2097152;          // 2097152
  float* dl   = ub + 2097152;          // 2097152
  float* Bb   = dl + 2097152;          // 262144
  float* Cb   = Bb + 262144;           // 262144
  float* chP  = Cb + 262144;           // 2097152
  float* chH  = chP + 2097152;         // 2097152 (Hl -> carry-in in place)
  float* opwT = chH + 2097152;         // 16384
  float* pp   = opwT + 16384;          // 8192

  k_prep<<<64, 256, 0, stream>>>(opw, opwT);
  k_linin<<<256, 256, 0, stream>>>(x, w_in, b_in, h);
  for (int i = 0; i < 2; ++i) {
    k_inproj<<<dim3(256, 4), 256, 0, stream>>>(h, ipw + i * 16384, xp, zb);
    k_mid<<<dim3(NC, 4), 256, 0, stream>>>(xp, cw + i * 512, cb + i * 128,
                                           xpw + i * 4608, dpw + i * 512, dpb + i * 128,
                                           Alog + i * 2048, ub, dl, Bb, Cb, chP, chH);
    k_scan2p<<<dim3(128, 4), 256, 0, stream>>>(chP, chH);
    k_back<<<dim3(NC, 4), 256, 0, stream>>>(ub, dl, Bb, Cb, zb, chH,
                                            Alog + i * 2048, Dsk + i * 128,
                                            opwT + i * 8192, h);
  }
  k_poolpart<<<dim3(32, 4), 256, 0, stream>>>(h, pp);
  k_cls<<<1, 256, 0, stream>>>(pp, wc, bc, out);
}